// Round 6
// baseline (323.950 us; speedup 1.0000x reference)
//
#include <hip/hip_runtime.h>

// Problem constants (B=1)
constexpr int L  = 2048;
constexpr int D  = 1024;
constexpr int H  = 16;
constexpr int F  = 16;   // qk feature dim per head
constexpr int HD = 64;   // v head dim
constexpr int CHUNK = 128;
constexpr int NC = L / CHUNK;  // 16

typedef __bf16 bf16x8 __attribute__((ext_vector_type(8)));
typedef float  f32x4  __attribute__((ext_vector_type(4)));

__device__ __forceinline__ ushort f2bf(float f) {
  uint u = __builtin_bit_cast(uint, f);
  uint r = (u + 0x7FFFu + ((u >> 16) & 1u)) >> 16;
  return (ushort)r;
}
__device__ __forceinline__ float bf2f(ushort h) {
  uint u = ((uint)h) << 16;
  return __builtin_bit_cast(float, u);
}

// ---------------------------------------------------------------------------
// hs fp32 -> Ah/Al bf16 hi/lo (layout-preserving, stride 1024).
// ---------------------------------------------------------------------------
__global__ __launch_bounds__(256) void split_hs(
    const float* __restrict__ X, ushort* __restrict__ Ah, ushort* __restrict__ Al) {
  int idx = blockIdx.x * 256 + threadIdx.x;        // float4 index
  if (idx >= L * D / 4) return;
  float4 v = ((const float4*)X)[idx];
  ushort4 h, l;
  h.x = f2bf(v.x); l.x = f2bf(v.x - bf2f(h.x));
  h.y = f2bf(v.y); l.y = f2bf(v.y - bf2f(h.y));
  h.z = f2bf(v.z); l.z = f2bf(v.z - bf2f(h.z));
  h.w = f2bf(v.w); l.w = f2bf(v.w - bf2f(h.w));
  ((ushort4*)Ah)[idx] = h;
  ((ushort4*)Al)[idx] = l;
}

// ---------------------------------------------------------------------------
// Weight W[k][n] fp32 -> BTh/BTl[n][k] bf16 (transpose + split). Grid (32,32).
// ---------------------------------------------------------------------------
__global__ __launch_bounds__(256) void wsplit_t(
    const float* __restrict__ W, ushort* __restrict__ BTh, ushort* __restrict__ BTl) {
  __shared__ float t[32][33];
  const int tid = threadIdx.x;
  const int lx = tid & 31, ly = tid >> 5;          // ly 0..7
  const int bn = blockIdx.x * 32, bk = blockIdx.y * 32;
  #pragma unroll
  for (int i = 0; i < 32; i += 8)
    t[ly + i][lx] = W[(size_t)(bk + ly + i) * 1024 + bn + lx];  // t[k][n]
  __syncthreads();
  #pragma unroll
  for (int i = 0; i < 32; i += 8) {
    float v = t[lx][ly + i];                        // k=bk+lx, n=bn+ly+i
    ushort hh = f2bf(v);
    ushort ll = f2bf(v - bf2f(hh));
    size_t base = (size_t)(bn + ly + i) * 1024 + bk + lx;
    BTh[base] = hh;
    BTl[base] = ll;
  }
}

// ---------------------------------------------------------------------------
// Virtual concat-K split GEMM: C[2048][N] fp32 = [Ah|Ah|Al] @ [Bh|Bl|Bh]^T
// (48 K-steps of 64 over virtual K=3072; source picked per step).
// BM=64, BN=128, BK=64, 512 thr = 8 waves (2x4), wave 32x32 = 2x2 frags of
// 16x16x32. Double-buffered LDS, reg-staged issue-early/write-late.
// ---------------------------------------------------------------------------
__global__ __launch_bounds__(512) void gemm_cc_v2(
    const ushort* __restrict__ Ah, const ushort* __restrict__ Al,
    const ushort* __restrict__ Bh, const ushort* __restrict__ Bl,
    float* __restrict__ C, int N) {
  constexpr int NSTEP = 48;
  constexpr int LDT = 72;          // bf16 per LDS row (144 B)
  __shared__ __bf16 As[2][64][LDT];
  __shared__ __bf16 Bs[2][128][LDT];
  const int tid  = threadIdx.x;
  const int wave = tid >> 6, lane = tid & 63;
  const int wm = (wave >> 2) * 32;     // 0/32
  const int wn = (wave & 3) * 32;      // 0..96
  const int brow = blockIdx.y * 64, bcol = blockIdx.x * 128;
  const int fr = lane & 15, kg = (lane >> 4) * 8;
  const int sr = tid >> 3, sc = (tid & 7) * 8;

  f32x4 acc[2][2];
  #pragma unroll
  for (int fm = 0; fm < 2; ++fm)
    #pragma unroll
    for (int fn = 0; fn < 2; ++fn)
      #pragma unroll
      for (int r = 0; r < 4; ++r) acc[fm][fn][r] = 0.f;

  bf16x8 ra, rb[2];
  auto LOADT = [&](int t) {
    const int k0 = ((t < 16) ? t : (t < 32) ? t - 16 : t - 32) * 64;
    const ushort* Asrc = (t < 32) ? Ah : Al;
    const ushort* Bsrc = (t < 16) ? Bh : (t < 32) ? Bl : Bh;
    ra = *(const bf16x8*)&Asrc[(size_t)(brow + sr) * 1024 + k0 + sc];
    #pragma unroll
    for (int i = 0; i < 2; ++i)
      rb[i] = *(const bf16x8*)&Bsrc[(size_t)(bcol + i * 64 + sr) * 1024 + k0 + sc];
  };
  auto WRITET = [&](int buf) {
    *(bf16x8*)&As[buf][sr][sc] = ra;
    #pragma unroll
    for (int i = 0; i < 2; ++i) *(bf16x8*)&Bs[buf][i * 64 + sr][sc] = rb[i];
  };

  LOADT(0); WRITET(0);
  __syncthreads();
  int cur = 0;
  for (int t = 0; t < NSTEP; ++t) {
    if (t + 1 < NSTEP) LOADT(t + 1);              // issue early
    bf16x8 af[2][2], bfr[2][2];
    #pragma unroll
    for (int fm = 0; fm < 2; ++fm)
      #pragma unroll
      for (int s = 0; s < 2; ++s)
        af[fm][s] = *(const bf16x8*)&As[cur][wm + fm * 16 + fr][s * 32 + kg];
    #pragma unroll
    for (int fn = 0; fn < 2; ++fn)
      #pragma unroll
      for (int s = 0; s < 2; ++s)
        bfr[fn][s] = *(const bf16x8*)&Bs[cur][wn + fn * 16 + fr][s * 32 + kg];
    #pragma unroll
    for (int s = 0; s < 2; ++s)
      #pragma unroll
      for (int fm = 0; fm < 2; ++fm)
        #pragma unroll
        for (int fn = 0; fn < 2; ++fn)
          acc[fm][fn] = __builtin_amdgcn_mfma_f32_16x16x32_bf16(
              af[fm][s], bfr[fn][s], acc[fm][fn], 0, 0, 0);
    if (t + 1 < NSTEP) WRITET(cur ^ 1);           // write late
    __syncthreads();
    cur ^= 1;
  }
  const int orow = (lane >> 4) * 4;
  #pragma unroll
  for (int fm = 0; fm < 2; ++fm)
    #pragma unroll
    for (int fn = 0; fn < 2; ++fn)
      #pragma unroll
      for (int r = 0; r < 4; ++r)
        C[(size_t)(brow + wm + fm * 16 + orow + r) * N + bcol + wn + fn * 16 + fr] =
            acc[fm][fn][r];
}

// ---------------------------------------------------------------------------
// Q/K projection, scalar fp64 accumulation (PROVEN structure from round 4),
// v4: same 64x64 tile but 512 threads (8 waves -> 2/SIMD for latency hiding;
// round-4 v3 ran at 1 wave/SIMD, VALUBusy 34%). Micro 2x4.
// A LDS [k][m] LDA=66 -> 4-address broadcast reads; B LDS [n][k] LDB=17 ->
// scalar reads, banks 2*tx mod 32 conflict-free. Double-buffered, reg-staged.
// Cols [0,256)->Q via Wq; else K via Wk. Grid (8, 32) = 256 blocks.
// ---------------------------------------------------------------------------
__global__ __launch_bounds__(512) void gemm_qk_f64_v4(
    const float* __restrict__ hs, const float* __restrict__ Wq, const float* __restrict__ Wk,
    float* __restrict__ Qo, float* __restrict__ Ko) {
  constexpr int LDA = 66;  // doubles per A k-row ([k][m], 64 used; 528B, 16B-aligned)
  constexpr int LDB = 17;  // doubles per B n-row ([n][k], 16 used; 136B)
  __shared__ double Asd[2][16][LDA];
  __shared__ double Bsd[2][64][LDB];
  const int tid = threadIdx.x;
  const int tx = tid & 15;         // col base: tx + 16*c
  const int ty = tid >> 4;         // rows ty*2 .. ty*2+1  (0..31)
  const int brow = blockIdx.y * 64;
  const int bcol = blockIdx.x * 64;        // 0..448
  const float* W = (bcol < 256) ? Wq : Wk;
  float* Out     = (bcol < 256) ? Qo : Ko;
  const int wcol = bcol & 255;

  const int am = tid >> 3, ak = (tid & 7) * 2;     // A staging: row am, k ak..ak+1
  const int bk = tid >> 5, bn = (tid & 31) * 2;    // B staging: k bk, cols bn..bn+1

  double acc[2][4] = {};

  float2 ra, rb;
  auto LOADT = [&](int k0) {
    ra = *(const float2*)&hs[(size_t)(brow + am) * D + k0 + ak];
    rb = *(const float2*)&W[(size_t)(k0 + bk) * 256 + wcol + bn];
  };
  auto WRITET = [&](int buf) {
    Asd[buf][ak + 0][am] = (double)ra.x; Asd[buf][ak + 1][am] = (double)ra.y;
    Bsd[buf][bn + 0][bk] = (double)rb.x; Bsd[buf][bn + 1][bk] = (double)rb.y;
  };

  LOADT(0); WRITET(0);
  __syncthreads();
  int cur = 0;
  for (int t = 0; t < D / 16; ++t) {
    if (t + 1 < D / 16) LOADT((t + 1) * 16);       // issue early
    #pragma unroll
    for (int k = 0; k < 16; ++k) {
      double a0 = Asd[cur][k][ty * 2];
      double a1 = Asd[cur][k][ty * 2 + 1];
      double b[4];
      #pragma unroll
      for (int c = 0; c < 4; ++c) b[c] = Bsd[cur][tx + 16 * c][k];
      #pragma unroll
      for (int c = 0; c < 4; ++c) {
        acc[0][c] = fma(a0, b[c], acc[0][c]);
        acc[1][c] = fma(a1, b[c], acc[1][c]);
      }
    }
    if (t + 1 < D / 16) WRITET(cur ^ 1);           // write late (other buffer)
    __syncthreads();
    cur ^= 1;
  }
  #pragma unroll
  for (int r = 0; r < 2; ++r)
    #pragma unroll
    for (int c = 0; c < 4; ++c)
      Out[(size_t)(brow + ty * 2 + r) * 256 + wcol + tx + 16 * c] = (float)acc[r][c];
}

// ---------------------------------------------------------------------------
// Per-chunk state sums: S[h][c][f][e] = sum_{m in chunk} k[m,h,f]*v[m,h,e];
// KS[h][c][f] = sum_m k[m,h,f] (fp64). Grid (NC, H), 256 threads.
// ---------------------------------------------------------------------------
__global__ __launch_bounds__(256) void chunk_state(
    const float* __restrict__ Kq, const float* __restrict__ V,
    float* __restrict__ S, double* __restrict__ KS) {
  const int c = blockIdx.x, h = blockIdx.y;
  __shared__ float Ks[CHUNK][F];
  __shared__ float Vs[CHUNK][HD];
  const int tid = threadIdx.x;
  #pragma unroll
  for (int i = 0; i < 2; ++i) {
    int g = i * 256 + tid;
    int m = g >> 2, f0 = (g & 3) * 4;
    *(float4*)&Ks[m][f0] = *(const float4*)&Kq[(size_t)(c * CHUNK + m) * (H * F) + h * F + f0];
  }
  #pragma unroll
  for (int i = 0; i < 8; ++i) {
    int g = i * 256 + tid;
    int m = g >> 4, e0 = (g & 15) * 4;
    *(float4*)&Vs[m][e0] = *(const float4*)&V[(size_t)(c * CHUNK + m) * (H * HD) + h * HD + e0];
  }
  __syncthreads();
  const int f = tid >> 4, e0 = (tid & 15) * 4;
  float4 acc = make_float4(0.f, 0.f, 0.f, 0.f);
  for (int m = 0; m < CHUNK; ++m) {
    float kv = Ks[m][f];
    float4 v4 = *(const float4*)&Vs[m][e0];
    acc.x = fmaf(kv, v4.x, acc.x);
    acc.y = fmaf(kv, v4.y, acc.y);
    acc.z = fmaf(kv, v4.z, acc.z);
    acc.w = fmaf(kv, v4.w, acc.w);
  }
  *(float4*)&S[((((size_t)h * NC) + c) * F + f) * HD + e0] = acc;
  if (tid < F) {
    double s = 0.0;
    for (int m = 0; m < CHUNK; ++m) s += (double)Ks[m][tid];
    KS[(((size_t)h * NC) + c) * F + tid] = s;
  }
}

// ---------------------------------------------------------------------------
// In-place exclusive prefix over chunks for S (fp32) and KS (fp64). Grid H.
// ---------------------------------------------------------------------------
__global__ void prefix_state(float* __restrict__ S, double* __restrict__ KS) {
  const int h = blockIdx.x;
  const int tid = threadIdx.x;
  float run = 0.f;
  for (int c = 0; c < NC; ++c) {
    size_t idx = (((size_t)h * NC) + c) * (F * HD) + tid;
    float v = S[idx];
    S[idx] = run;
    run += v;
  }
  if (tid < F) {
    double rk = 0.0;
    for (int c = 0; c < NC; ++c) {
      size_t idx = (((size_t)h * NC) + c) * F + tid;
      double v = KS[idx];
      KS[idx] = rk;
      rk += v;
    }
  }
}

// ---------------------------------------------------------------------------
// Fused chunk attention; writes Ys as bf16 hi/lo (stride 1024). Grid (NC, H).
// ---------------------------------------------------------------------------
__global__ __launch_bounds__(256) void attn_chunk(
    const float* __restrict__ Q, const float* __restrict__ Kq, const float* __restrict__ V,
    const float* __restrict__ Sin, const double* __restrict__ kcum,
    ushort* __restrict__ Yh, ushort* __restrict__ Yl) {
  const int c = blockIdx.x, h = blockIdx.y;
  __shared__ float Ks[CHUNK][F];
  __shared__ float Vs[CHUNK][HD];
  __shared__ float Ss[F][HD];
  __shared__ double kcs[F];
  __shared__ float zs[CHUNK];
  const int tid = threadIdx.x;

  #pragma unroll
  for (int i = 0; i < 2; ++i) {
    int g = i * 256 + tid;
    int m = g >> 2, f0 = (g & 3) * 4;
    *(float4*)&Ks[m][f0] = *(const float4*)&Kq[(size_t)(c * CHUNK + m) * (H * F) + h * F + f0];
  }
  #pragma unroll
  for (int i = 0; i < 8; ++i) {
    int g = i * 256 + tid;
    int m = g >> 4, e0 = (g & 15) * 4;
    *(float4*)&Vs[m][e0] = *(const float4*)&V[(size_t)(c * CHUNK + m) * (H * HD) + h * HD + e0];
  }
  {
    int f = tid >> 4, e0 = (tid & 15) * 4;
    *(float4*)&Ss[f][e0] = *(const float4*)&Sin[(((size_t)h * NC) + c) * (F * HD) + f * HD + e0];
  }
  if (tid < F) kcs[tid] = kcum[(((size_t)h * NC) + c) * F + tid];
  __syncthreads();

  const int rg = tid >> 3;
  const int cg = tid & 7;
  const int i0 = rg * 4;
  const int e0 = cg * 8;

  float q[4][F];
  #pragma unroll
  for (int r = 0; r < 4; ++r)
    #pragma unroll
    for (int f0 = 0; f0 < F; f0 += 4)
      *(float4*)&q[r][f0] = *(const float4*)&Q[(size_t)(c * CHUNK + i0 + r) * (H * F) + h * F + f0];

  float acc[4][8];
  #pragma unroll
  for (int r = 0; r < 4; ++r)
    #pragma unroll
    for (int j = 0; j < 8; ++j) acc[r][j] = 0.f;
  float den[4] = {0.f, 0.f, 0.f, 0.f};

  const int mmax = ((tid >> 6) + 1) * 32;
  for (int m = 0; m < mmax; ++m) {
    float kr[F];
    #pragma unroll
    for (int f0 = 0; f0 < F; f0 += 4)
      *(float4*)&kr[f0] = *(const float4*)&Ks[m][f0];
    float a[4];
    #pragma unroll
    for (int r = 0; r < 4; ++r) {
      float s = 0.f;
      #pragma unroll
      for (int f = 0; f < F; ++f) s = fmaf(q[r][f], kr[f], s);
      a[r] = (m <= i0 + r) ? s : 0.f;
      den[r] += a[r];
    }
    float v8[8];
    *(float4*)&v8[0] = *(const float4*)&Vs[m][e0];
    *(float4*)&v8[4] = *(const float4*)&Vs[m][e0 + 4];
    #pragma unroll
    for (int r = 0; r < 4; ++r)
      #pragma unroll
      for (int j = 0; j < 8; ++j)
        acc[r][j] = fmaf(a[r], v8[j], acc[r][j]);
  }

  #pragma unroll
  for (int f = 0; f < F; ++f) {
    float s8[8];
    *(float4*)&s8[0] = *(const float4*)&Ss[f][e0];
    *(float4*)&s8[4] = *(const float4*)&Ss[f][e0 + 4];
    #pragma unroll
    for (int r = 0; r < 4; ++r)
      #pragma unroll
      for (int j = 0; j < 8; ++j)
        acc[r][j] = fmaf(q[r][f], s8[j], acc[r][j]);
  }

  if (cg == 0) {
    #pragma unroll
    for (int r = 0; r < 4; ++r) {
      double dd = (double)den[r];
      #pragma unroll
      for (int f = 0; f < F; ++f) dd += (double)q[r][f] * kcs[f];
      zs[i0 + r] = (float)(1.0 / (dd + 1e-12));
    }
  }
  __syncthreads();

  #pragma unroll
  for (int r = 0; r < 4; ++r) {
    float zz = zs[i0 + r];
    ushort4 h4a, h4b, l4a, l4b;
    float o;
    o = acc[r][0] * zz; h4a.x = f2bf(o); l4a.x = f2bf(o - bf2f(h4a.x));
    o = acc[r][1] * zz; h4a.y = f2bf(o); l4a.y = f2bf(o - bf2f(h4a.y));
    o = acc[r][2] * zz; h4a.z = f2bf(o); l4a.z = f2bf(o - bf2f(h4a.z));
    o = acc[r][3] * zz; h4a.w = f2bf(o); l4a.w = f2bf(o - bf2f(h4a.w));
    o = acc[r][4] * zz; h4b.x = f2bf(o); l4b.x = f2bf(o - bf2f(h4b.x));
    o = acc[r][5] * zz; h4b.y = f2bf(o); l4b.y = f2bf(o - bf2f(h4b.y));
    o = acc[r][6] * zz; h4b.z = f2bf(o); l4b.z = f2bf(o - bf2f(h4b.z));
    o = acc[r][7] * zz; h4b.w = f2bf(o); l4b.w = f2bf(o - bf2f(h4b.w));
    size_t base = (size_t)(c * CHUNK + i0 + r) * 1024 + h * HD + e0;
    *(ushort4*)&Yh[base]     = h4a;
    *(ushort4*)&Yh[base + 4] = h4b;
    *(ushort4*)&Yl[base]     = l4a;
    *(ushort4*)&Yl[base + 4] = l4b;
  }
}

// ---------------------------------------------------------------------------
extern "C" void kernel_launch(void* const* d_in, const int* in_sizes, int n_in,
                              void* d_out, int out_size, void* d_ws, size_t ws_size,
                              hipStream_t stream) {
  const float* hs = (const float*)d_in[0];
  const float* Wq = (const float*)d_in[1];
  const float* Wk = (const float*)d_in[2];
  const float* Wv = (const float*)d_in[3];
  const float* Wo = (const float*)d_in[4];
  float* out = (float*)d_out;

  char* ws = (char*)d_ws;
  const size_t MB = 1 << 20;
  ushort* Ah  = (ushort*)(ws + 0 * MB);    // 4 MB [2048][1024] bf16 (hs_hi, then Ys_hi)
  ushort* Al  = (ushort*)(ws + 4 * MB);    // 4 MB (hs_lo, then Ys_lo)
  ushort* Bh  = (ushort*)(ws + 8 * MB);    // 2 MB [1024][1024] bf16 (WvT_hi, then WoT_hi)
  ushort* Bl  = (ushort*)(ws + 10 * MB);   // 2 MB
  float*  Vb  = (float*)(ws + 12 * MB);    // 8 MB [2048][1024] fp32
  float*  Qb  = (float*)(ws + 20 * MB);    // 2 MB [2048][256]
  float*  Kb  = (float*)(ws + 22 * MB);    // 2 MB
  float*  S   = (float*)(ws + 24 * MB);    // 1 MB [H][NC][F][HD] (Sc -> Sin in place)
  // KS in d_out (8 MB): scratch for steps 5-8, fully overwritten by step 9.
  double* KS  = (double*)d_out;            // 32 KB [H][NC][F]

  // 1) hs -> bf16 hi/lo
  split_hs<<<dim3(L * D / 4 / 256), 256, 0, stream>>>(hs, Ah, Al);
  // 2) Wv -> transposed bf16 hi/lo
  wsplit_t<<<dim3(32, 32), 256, 0, stream>>>(Wv, Bh, Bl);
  // 3) Q,K projection (scalar fp64 accumulate, 8-wave blocks)
  gemm_qk_f64_v4<<<dim3(8, 32), 512, 0, stream>>>(hs, Wq, Wk, Qb, Kb);
  // 4) V projection (virtual concat-K split GEMM)
  gemm_cc_v2<<<dim3(1024 / 128, 2048 / 64), 512, 0, stream>>>(Ah, Al, Bh, Bl, Vb, 1024);
  // 5) per-chunk k^T v states + fp64 k sums
  chunk_state<<<dim3(NC, H), 256, 0, stream>>>(Kb, Vb, S, KS);
  // 6) in-place exclusive prefix over chunks
  prefix_state<<<H, 1024, 0, stream>>>(S, KS);
  // 7) Wo -> transposed bf16 hi/lo (Wv splits dead after step 4)
  wsplit_t<<<dim3(32, 32), 256, 0, stream>>>(Wo, Bh, Bl);
  // 8) fused chunk attention -> Ys hi/lo (overwrites hs splits)
  attn_chunk<<<dim3(NC, H), 256, 0, stream>>>(Qb, Kb, Vb, S, KS, Ah, Al);
  // 9) output projection (fully overwrites d_out, retiring KS scratch)
  gemm_cc_v2<<<dim3(1024 / 128, 2048 / 64), 512, 0, stream>>>(Ah, Al, Bh, Bl, out, 1024);
}

// Round 7
// 150.898 us; speedup vs baseline: 2.1468x; 2.1468x over previous
//
#include <hip/hip_runtime.h>

// Problem constants (B=1)
constexpr int L  = 2048;
constexpr int D  = 1024;
constexpr int H  = 16;
constexpr int F  = 16;   // qk feature dim per head
constexpr int HD = 64;   // v head dim
constexpr int CHUNK = 128;
constexpr int NC = L / CHUNK;  // 16

typedef __bf16 bf16x8 __attribute__((ext_vector_type(8)));
typedef float  f32x16 __attribute__((ext_vector_type(16)));
typedef int    i32x4  __attribute__((ext_vector_type(4)));

__device__ __forceinline__ ushort f2bf(float f) {
  uint u = __builtin_bit_cast(uint, f);
  uint r = (u + 0x7FFFu + ((u >> 16) & 1u)) >> 16;
  return (ushort)r;
}
__device__ __forceinline__ float bf2f(ushort h) {
  uint u = ((uint)h) << 16;
  return __builtin_bit_cast(float, u);
}

// 5-slice signed-7-bit split of fp32 (scales 2^-4,2^-11,2^-18,2^-25,2^-32).
// Exact reconstruction for |x| >= 2^-13; residual <= 2^-33 otherwise.
__device__ __forceinline__ void split5(float x, signed char s[5]) {
  float t = rintf(x * 16.f);              s[0] = (signed char)t;
  float r = fmaf(t, -6.25e-2f, x);
  t = rintf(r * 2048.f);                  s[1] = (signed char)t;
  r = fmaf(t, -4.8828125e-4f, r);
  t = rintf(r * 262144.f);                s[2] = (signed char)t;
  r = fmaf(t, -3.814697265625e-6f, r);
  t = rintf(r * 33554432.f);              s[3] = (signed char)t;
  r = fmaf(t, -2.9802322387695312e-8f, r);
  t = rintf(r * 4294967296.f);            s[4] = (signed char)t;
}

// ---------------------------------------------------------------------------
// hs fp32 -> Ah/Al bf16 hi/lo (layout-preserving, stride 1024).  [round-2 proven]
// ---------------------------------------------------------------------------
__global__ __launch_bounds__(256) void split_hs(
    const float* __restrict__ X, ushort* __restrict__ Ah, ushort* __restrict__ Al) {
  int idx = blockIdx.x * 256 + threadIdx.x;
  if (idx >= L * D / 4) return;
  float4 v = ((const float4*)X)[idx];
  ushort4 h, l;
  h.x = f2bf(v.x); l.x = f2bf(v.x - bf2f(h.x));
  h.y = f2bf(v.y); l.y = f2bf(v.y - bf2f(h.y));
  h.z = f2bf(v.z); l.z = f2bf(v.z - bf2f(h.z));
  h.w = f2bf(v.w); l.w = f2bf(v.w - bf2f(h.w));
  ((ushort4*)Ah)[idx] = h;
  ((ushort4*)Al)[idx] = l;
}

// ---------------------------------------------------------------------------
// Weight W[k][n] fp32 -> BTh/BTl[n][k] bf16 (transpose + split). [proven]
// ---------------------------------------------------------------------------
__global__ __launch_bounds__(256) void wsplit_t(
    const float* __restrict__ W, ushort* __restrict__ BTh, ushort* __restrict__ BTl) {
  __shared__ float t[32][33];
  const int tid = threadIdx.x;
  const int lx = tid & 31, ly = tid >> 5;
  const int bn = blockIdx.x * 32, bk = blockIdx.y * 32;
  #pragma unroll
  for (int i = 0; i < 32; i += 8)
    t[ly + i][lx] = W[(size_t)(bk + ly + i) * 1024 + bn + lx];
  __syncthreads();
  #pragma unroll
  for (int i = 0; i < 32; i += 8) {
    float v = t[lx][ly + i];
    ushort hh = f2bf(v);
    ushort ll = f2bf(v - bf2f(hh));
    size_t base = (size_t)(bn + ly + i) * 1024 + bk + lx;
    BTh[base] = hh;
    BTl[base] = ll;
  }
}

// ---------------------------------------------------------------------------
// hs -> 5 int8 slice planes A8[s][2048][1024].
// ---------------------------------------------------------------------------
__global__ __launch_bounds__(256) void split_i8_hs(
    const float* __restrict__ X, signed char* __restrict__ A8) {
  const int plane = L * D;
  int idx = blockIdx.x * 256 + threadIdx.x;
  if (idx >= plane / 4) return;
  float4 v = ((const float4*)X)[idx];
  signed char sx[5], sy[5], sz[5], sw[5];
  split5(v.x, sx); split5(v.y, sy); split5(v.z, sz); split5(v.w, sw);
  #pragma unroll
  for (int s = 0; s < 5; ++s) {
    char4 c; c.x = sx[s]; c.y = sy[s]; c.z = sz[s]; c.w = sw[s];
    ((char4*)(A8 + (size_t)s * plane))[idx] = c;
  }
}

// ---------------------------------------------------------------------------
// [Wq|Wk] (each [1024][256]) -> transposed 5-slice int8 W8[s][512][1024].
// Grid (16, 32): bn = n-tile (0..511), bk = k-tile.
// ---------------------------------------------------------------------------
__global__ __launch_bounds__(256) void wsplit_i8(
    const float* __restrict__ Wq, const float* __restrict__ Wk,
    signed char* __restrict__ W8) {
  const int plane = 512 * 1024;
  __shared__ float t[32][33];
  const int tid = threadIdx.x;
  const int lx = tid & 31, ly = tid >> 5;
  const int bn = blockIdx.x * 32, bk = blockIdx.y * 32;
  const float* W = (bn < 256) ? Wq : Wk;
  const int wn = bn & 255;
  #pragma unroll
  for (int i = 0; i < 32; i += 8)
    t[ly + i][lx] = W[(size_t)(bk + ly + i) * 256 + wn + lx];   // t[k][n]
  __syncthreads();
  #pragma unroll
  for (int i = 0; i < 32; i += 8) {
    float v = t[lx][ly + i];                 // k=bk+lx, n=bn+ly+i
    signed char s[5];
    split5(v, s);
    size_t base = (size_t)(bn + ly + i) * 1024 + bk + lx;
    #pragma unroll
    for (int si = 0; si < 5; ++si) W8[(size_t)si * plane + base] = s[si];
  }
}

// ---------------------------------------------------------------------------
// Exact QK projection via int8 MFMA (Ozaki-style 5-slice, 15 pairs i+j<=4,
// i32 accumulation is exact; grouped by g=i+j, fp64 reconstruction).
// C[2048][512]: cols<256 -> Qb, else Kb. Tile 64x64, BK=64, 512 thr = 8 waves
// (2x4), wave 32x16 = 2x1 frags of mfma_i32_16x16x64_i8. Grid (8,32).
// ---------------------------------------------------------------------------
__global__ __launch_bounds__(512) void gemm_qk_i8(
    const signed char* __restrict__ A8, const signed char* __restrict__ W8,
    float* __restrict__ Qo, float* __restrict__ Ko) {
  constexpr int LDT = 80;                 // bytes per LDS row (16B-aligned)
  __shared__ signed char As[5][64][LDT];  // 25.6 KB
  __shared__ signed char Bs[5][64][LDT];  // 25.6 KB
  const int aplane = L * D;               // 2M
  const int bplane = 512 * 1024;
  const int tid  = threadIdx.x;
  const int wave = tid >> 6, lane = tid & 63;
  const int wm = (wave >> 2) * 32;        // 0/32
  const int wn = (wave & 3) * 16;         // 0/16/32/48
  const int brow = blockIdx.y * 64, bcol = blockIdx.x * 64;
  const int fr = lane & 15, kq = (lane >> 4) * 16;

  i32x4 acc[2][5];
  #pragma unroll
  for (int fm = 0; fm < 2; ++fm)
    #pragma unroll
    for (int g = 0; g < 5; ++g)
      #pragma unroll
      for (int r = 0; r < 4; ++r) acc[fm][g][r] = 0;

  for (int k0 = 0; k0 < D; k0 += 64) {
    // stage 2560 16B-chunks (5 slices x 64 rows x 4 chunks x 2 sides), 5/thread
    #pragma unroll
    for (int i = 0; i < 5; ++i) {
      int c = i * 512 + tid;
      int side = (c >= 1280);
      int cc = side ? c - 1280 : c;
      int slice = cc >> 8, row = (cc & 255) >> 2, c16 = (cc & 3) * 16;
      const signed char* src = side
          ? &W8[(size_t)slice * bplane + (size_t)(bcol + row) * 1024 + k0 + c16]
          : &A8[(size_t)slice * aplane + (size_t)(brow + row) * 1024 + k0 + c16];
      int4 val = *(const int4*)src;
      signed char* dst = side ? &Bs[slice][row][c16] : &As[slice][row][c16];
      *(int4*)dst = val;
    }
    __syncthreads();
    i32x4 bfr[5], afr[2][5];
    #pragma unroll
    for (int s = 0; s < 5; ++s) bfr[s] = *(const i32x4*)&Bs[s][wn + fr][kq];
    #pragma unroll
    for (int fm = 0; fm < 2; ++fm)
      #pragma unroll
      for (int s = 0; s < 5; ++s)
        afr[fm][s] = *(const i32x4*)&As[s][wm + fm * 16 + fr][kq];
    #pragma unroll
    for (int fm = 0; fm < 2; ++fm) {
      acc[fm][0] = __builtin_amdgcn_mfma_i32_16x16x64_i8(afr[fm][0], bfr[0], acc[fm][0], 0, 0, 0);
      #pragma unroll
      for (int g = 1; g < 5; ++g)
        #pragma unroll
        for (int i = 0; i <= g; ++i)
          acc[fm][g] = __builtin_amdgcn_mfma_i32_16x16x64_i8(afr[fm][i], bfr[g - i], acc[fm][g], 0, 0, 0);
    }
    __syncthreads();
  }
  // reconstruct: sum_g acc_g * 2^(-8-7g); C/D: col=lane&15, row=(lane>>4)*4+r
  const double sc0 = 3.90625e-3, sc1 = 3.0517578125e-5, sc2 = 2.384185791015625e-7,
               sc3 = 1.862645149230957e-9, sc4 = 1.4551915228366852e-11;
  float* Out = (bcol < 256) ? Qo : Ko;
  const int ocol = (bcol & 255) + wn + fr;
  #pragma unroll
  for (int fm = 0; fm < 2; ++fm)
    #pragma unroll
    for (int r = 0; r < 4; ++r) {
      double v = (double)acc[fm][0][r] * sc0 + (double)acc[fm][1][r] * sc1 +
                 (double)acc[fm][2][r] * sc2 + (double)acc[fm][3][r] * sc3 +
                 (double)acc[fm][4][r] * sc4;
      int row = brow + wm + fm * 16 + (lane >> 4) * 4 + r;
      Out[(size_t)row * 256 + ocol] = (float)v;
    }
}

// ---------------------------------------------------------------------------
// bf16x2-split GEMM with MFMA  [round-2 proven verbatim]:
// C = Ah@B + Al@B with BT hi/lo; 6 x mfma_f32_32x32x16_bf16 per K-step.
// Tile 64x64, BK=32, 256 thr = 4 waves; grid (N/64, M/64).
// ---------------------------------------------------------------------------
__global__ __launch_bounds__(256) void gemm_split_bf16(
    const ushort* __restrict__ Ah, const ushort* __restrict__ Al,
    const ushort* __restrict__ BTh, const ushort* __restrict__ BTl,
    float* __restrict__ C, int M, int N, int K) {
  constexpr int LDT = 40;
  __shared__ __bf16 As[2][64][LDT];
  __shared__ __bf16 Bs[2][64][LDT];
  const int tid  = threadIdx.x;
  const int wave = tid >> 6, lane = tid & 63;
  const int wr = (wave >> 1) * 32, wc = (wave & 1) * 32;
  const int brow = blockIdx.y * 64, bcol = blockIdx.x * 64;
  const int srow = tid >> 2, skg = (tid & 3) * 8;
  const size_t a_off = (size_t)(brow + srow) * K + skg;
  const size_t b_off = (size_t)(bcol + srow) * K + skg;

  f32x16 acc;
  #pragma unroll
  for (int i = 0; i < 16; ++i) acc[i] = 0.f;

  for (int k0 = 0; k0 < K; k0 += 32) {
    *(bf16x8*)&As[0][srow][skg] = *(const bf16x8*)&Ah[a_off + k0];
    *(bf16x8*)&As[1][srow][skg] = *(const bf16x8*)&Al[a_off + k0];
    *(bf16x8*)&Bs[0][srow][skg] = *(const bf16x8*)&BTh[b_off + k0];
    *(bf16x8*)&Bs[1][srow][skg] = *(const bf16x8*)&BTl[b_off + k0];
    __syncthreads();
    const int fr = lane & 31;
    const int kh = (lane >> 5) * 8;
    bf16x8 ah0 = *(const bf16x8*)&As[0][wr + fr][kh];
    bf16x8 ah1 = *(const bf16x8*)&As[0][wr + fr][16 + kh];
    bf16x8 al0 = *(const bf16x8*)&As[1][wr + fr][kh];
    bf16x8 al1 = *(const bf16x8*)&As[1][wr + fr][16 + kh];
    bf16x8 bh0 = *(const bf16x8*)&Bs[0][wc + fr][kh];
    bf16x8 bh1 = *(const bf16x8*)&Bs[0][wc + fr][16 + kh];
    bf16x8 bl0 = *(const bf16x8*)&Bs[1][wc + fr][kh];
    bf16x8 bl1 = *(const bf16x8*)&Bs[1][wc + fr][16 + kh];
    acc = __builtin_amdgcn_mfma_f32_32x32x16_bf16(ah0, bh0, acc, 0, 0, 0);
    acc = __builtin_amdgcn_mfma_f32_32x32x16_bf16(ah1, bh1, acc, 0, 0, 0);
    acc = __builtin_amdgcn_mfma_f32_32x32x16_bf16(ah0, bl0, acc, 0, 0, 0);
    acc = __builtin_amdgcn_mfma_f32_32x32x16_bf16(ah1, bl1, acc, 0, 0, 0);
    acc = __builtin_amdgcn_mfma_f32_32x32x16_bf16(al0, bh0, acc, 0, 0, 0);
    acc = __builtin_amdgcn_mfma_f32_32x32x16_bf16(al1, bh1, acc, 0, 0, 0);
    __syncthreads();
  }
  const int fr = lane & 31, fq = lane >> 5;
  #pragma unroll
  for (int r = 0; r < 16; ++r) {
    int row = brow + wr + (r & 3) + 8 * (r >> 2) + 4 * fq;
    C[(size_t)row * N + bcol + wc + fr] = acc[r];
  }
}

// ---------------------------------------------------------------------------
// Per-chunk state sums  [proven]. Grid (NC, H), 256 threads.
// ---------------------------------------------------------------------------
__global__ __launch_bounds__(256) void chunk_state(
    const float* __restrict__ Kq, const float* __restrict__ V,
    float* __restrict__ S, double* __restrict__ KS) {
  const int c = blockIdx.x, h = blockIdx.y;
  __shared__ float Ks[CHUNK][F];
  __shared__ float Vs[CHUNK][HD];
  const int tid = threadIdx.x;
  #pragma unroll
  for (int i = 0; i < 2; ++i) {
    int g = i * 256 + tid;
    int m = g >> 2, f0 = (g & 3) * 4;
    *(float4*)&Ks[m][f0] = *(const float4*)&Kq[(size_t)(c * CHUNK + m) * (H * F) + h * F + f0];
  }
  #pragma unroll
  for (int i = 0; i < 8; ++i) {
    int g = i * 256 + tid;
    int m = g >> 4, e0 = (g & 15) * 4;
    *(float4*)&Vs[m][e0] = *(const float4*)&V[(size_t)(c * CHUNK + m) * (H * HD) + h * HD + e0];
  }
  __syncthreads();
  const int f = tid >> 4, e0 = (tid & 15) * 4;
  float4 acc = make_float4(0.f, 0.f, 0.f, 0.f);
  for (int m = 0; m < CHUNK; ++m) {
    float kv = Ks[m][f];
    float4 v4 = *(const float4*)&Vs[m][e0];
    acc.x = fmaf(kv, v4.x, acc.x);
    acc.y = fmaf(kv, v4.y, acc.y);
    acc.z = fmaf(kv, v4.z, acc.z);
    acc.w = fmaf(kv, v4.w, acc.w);
  }
  *(float4*)&S[((((size_t)h * NC) + c) * F + f) * HD + e0] = acc;
  if (tid < F) {
    double s = 0.0;
    for (int m = 0; m < CHUNK; ++m) s += (double)Ks[m][tid];
    KS[(((size_t)h * NC) + c) * F + tid] = s;
  }
}

// ---------------------------------------------------------------------------
// In-place exclusive prefix over chunks  [proven]. Grid H.
// ---------------------------------------------------------------------------
__global__ void prefix_state(float* __restrict__ S, double* __restrict__ KS) {
  const int h = blockIdx.x;
  const int tid = threadIdx.x;
  float run = 0.f;
  for (int c = 0; c < NC; ++c) {
    size_t idx = (((size_t)h * NC) + c) * (F * HD) + tid;
    float v = S[idx];
    S[idx] = run;
    run += v;
  }
  if (tid < F) {
    double rk = 0.0;
    for (int c = 0; c < NC; ++c) {
      size_t idx = (((size_t)h * NC) + c) * F + tid;
      double v = KS[idx];
      KS[idx] = rk;
      rk += v;
    }
  }
}

// ---------------------------------------------------------------------------
// Fused chunk attention -> Ys bf16 hi/lo (stride 1024)  [proven]. Grid (NC,H).
// ---------------------------------------------------------------------------
__global__ __launch_bounds__(256) void attn_chunk(
    const float* __restrict__ Q, const float* __restrict__ Kq, const float* __restrict__ V,
    const float* __restrict__ Sin, const double* __restrict__ kcum,
    ushort* __restrict__ Yh, ushort* __restrict__ Yl) {
  const int c = blockIdx.x, h = blockIdx.y;
  __shared__ float Ks[CHUNK][F];
  __shared__ float Vs[CHUNK][HD];
  __shared__ float Ss[F][HD];
  __shared__ double kcs[F];
  __shared__ float zs[CHUNK];
  const int tid = threadIdx.x;

  #pragma unroll
  for (int i = 0; i < 2; ++i) {
    int g = i * 256 + tid;
    int m = g >> 2, f0 = (g & 3) * 4;
    *(float4*)&Ks[m][f0] = *(const float4*)&Kq[(size_t)(c * CHUNK + m) * (H * F) + h * F + f0];
  }
  #pragma unroll
  for (int i = 0; i < 8; ++i) {
    int g = i * 256 + tid;
    int m = g >> 4, e0 = (g & 15) * 4;
    *(float4*)&Vs[m][e0] = *(const float4*)&V[(size_t)(c * CHUNK + m) * (H * HD) + h * HD + e0];
  }
  {
    int f = tid >> 4, e0 = (tid & 15) * 4;
    *(float4*)&Ss[f][e0] = *(const float4*)&Sin[(((size_t)h * NC) + c) * (F * HD) + f * HD + e0];
  }
  if (tid < F) kcs[tid] = kcum[(((size_t)h * NC) + c) * F + tid];
  __syncthreads();

  const int rg = tid >> 3;
  const int cg = tid & 7;
  const int i0 = rg * 4;
  const int e0 = cg * 8;

  float q[4][F];
  #pragma unroll
  for (int r = 0; r < 4; ++r)
    #pragma unroll
    for (int f0 = 0; f0 < F; f0 += 4)
      *(float4*)&q[r][f0] = *(const float4*)&Q[(size_t)(c * CHUNK + i0 + r) * (H * F) + h * F + f0];

  float acc[4][8];
  #pragma unroll
  for (int r = 0; r < 4; ++r)
    #pragma unroll
    for (int j = 0; j < 8; ++j) acc[r][j] = 0.f;
  float den[4] = {0.f, 0.f, 0.f, 0.f};

  const int mmax = ((tid >> 6) + 1) * 32;
  for (int m = 0; m < mmax; ++m) {
    float kr[F];
    #pragma unroll
    for (int f0 = 0; f0 < F; f0 += 4)
      *(float4*)&kr[f0] = *(const float4*)&Ks[m][f0];
    float a[4];
    #pragma unroll
    for (int r = 0; r < 4; ++r) {
      float s = 0.f;
      #pragma unroll
      for (int f = 0; f < F; ++f) s = fmaf(q[r][f], kr[f], s);
      a[r] = (m <= i0 + r) ? s : 0.f;
      den[r] += a[r];
    }
    float v8[8];
    *(float4*)&v8[0] = *(const float4*)&Vs[m][e0];
    *(float4*)&v8[4] = *(const float4*)&Vs[m][e0 + 4];
    #pragma unroll
    for (int r = 0; r < 4; ++r)
      #pragma unroll
      for (int j = 0; j < 8; ++j)
        acc[r][j] = fmaf(a[r], v8[j], acc[r][j]);
  }

  #pragma unroll
  for (int f = 0; f < F; ++f) {
    float s8[8];
    *(float4*)&s8[0] = *(const float4*)&Ss[f][e0];
    *(float4*)&s8[4] = *(const float4*)&Ss[f][e0 + 4];
    #pragma unroll
    for (int r = 0; r < 4; ++r)
      #pragma unroll
      for (int j = 0; j < 8; ++j)
        acc[r][j] = fmaf(q[r][f], s8[j], acc[r][j]);
  }

  if (cg == 0) {
    #pragma unroll
    for (int r = 0; r < 4; ++r) {
      double dd = (double)den[r];
      #pragma unroll
      for (int f = 0; f < F; ++f) dd += (double)q[r][f] * kcs[f];
      zs[i0 + r] = (float)(1.0 / (dd + 1e-12));
    }
  }
  __syncthreads();

  #pragma unroll
  for (int r = 0; r < 4; ++r) {
    float zz = zs[i0 + r];
    ushort4 h4a, h4b, l4a, l4b;
    float o;
    o = acc[r][0] * zz; h4a.x = f2bf(o); l4a.x = f2bf(o - bf2f(h4a.x));
    o = acc[r][1] * zz; h4a.y = f2bf(o); l4a.y = f2bf(o - bf2f(h4a.y));
    o = acc[r][2] * zz; h4a.z = f2bf(o); l4a.z = f2bf(o - bf2f(h4a.z));
    o = acc[r][3] * zz; h4a.w = f2bf(o); l4a.w = f2bf(o - bf2f(h4a.w));
    o = acc[r][4] * zz; h4b.x = f2bf(o); l4b.x = f2bf(o - bf2f(h4b.x));
    o = acc[r][5] * zz; h4b.y = f2bf(o); l4b.y = f2bf(o - bf2f(h4b.y));
    o = acc[r][6] * zz; h4b.z = f2bf(o); l4b.z = f2bf(o - bf2f(h4b.z));
    o = acc[r][7] * zz; h4b.w = f2bf(o); l4b.w = f2bf(o - bf2f(h4b.w));
    size_t base = (size_t)(c * CHUNK + i0 + r) * 1024 + h * HD + e0;
    *(ushort4*)&Yh[base]     = h4a;
    *(ushort4*)&Yh[base + 4] = h4b;
    *(ushort4*)&Yl[base]     = l4a;
    *(ushort4*)&Yl[base + 4] = l4b;
  }
}

// ---------------------------------------------------------------------------
extern "C" void kernel_launch(void* const* d_in, const int* in_sizes, int n_in,
                              void* d_out, int out_size, void* d_ws, size_t ws_size,
                              hipStream_t stream) {
  const float* hs = (const float*)d_in[0];
  const float* Wq = (const float*)d_in[1];
  const float* Wk = (const float*)d_in[2];
  const float* Wv = (const float*)d_in[3];
  const float* Wo = (const float*)d_in[4];
  float* out = (float*)d_out;

  char* ws = (char*)d_ws;
  const size_t MB = 1 << 20;
  ushort* Ah   = (ushort*)(ws + 0 * MB);        // 4 MB hs_hi -> later Ys_hi
  ushort* Al   = (ushort*)(ws + 4 * MB);        // 4 MB hs_lo -> later Ys_lo
  ushort* Bh   = (ushort*)(ws + 8 * MB);        // 2 MB WvT_hi
  ushort* Bl   = (ushort*)(ws + 10 * MB);       // 2 MB WvT_lo
  signed char* A8 = (signed char*)(ws + 0 * MB);   // 10 MB (overlays Ah/Al/Bh after V-GEMM)
  signed char* W8 = (signed char*)(ws + 10 * MB);  // 2.5 MB (overlays Bl)
  float*  Vb   = (float*)(ws + 13 * MB);        // 8 MB
  float*  Qb   = (float*)(ws + 21 * MB);        // 2 MB
  float*  Kb   = (float*)(ws + 23 * MB);        // 2 MB
  float*  S    = (float*)(ws + 25 * MB);        // 1 MB
  ushort* WoTh = (ushort*)(ws + 26 * MB);       // 2 MB
  ushort* WoTl = (ushort*)(ws + 28 * MB);       // 2 MB  (peak 30 MB)
  double* KS   = (double*)d_out;                // 32 KB scratch, retired by step 10

  // 1) hs -> bf16 hi/lo
  split_hs<<<dim3(L * D / 4 / 256), 256, 0, stream>>>(hs, Ah, Al);
  // 2) Wv -> transposed bf16 hi/lo
  wsplit_t<<<dim3(32, 32), 256, 0, stream>>>(Wv, Bh, Bl);
  // 3) V projection (round-2 proven split GEMM)
  gemm_split_bf16<<<dim3(16, 32), 256, 0, stream>>>(Ah, Al, Bh, Bl, Vb, L, 1024, D);
  // 4) int8 5-slice splits (overwrite hs/Wv split buffers, now dead)
  split_i8_hs<<<dim3(L * D / 4 / 256), 256, 0, stream>>>(hs, A8);
  wsplit_i8<<<dim3(16, 32), 256, 0, stream>>>(Wq, Wk, W8);
  // 5) exact QK projection via i8 MFMA
  gemm_qk_i8<<<dim3(8, 32), 512, 0, stream>>>(A8, W8, Qb, Kb);
  // 6) per-chunk k^T v states + fp64 k sums
  chunk_state<<<dim3(NC, H), 256, 0, stream>>>(Kb, Vb, S, KS);
  // 7) in-place exclusive prefix over chunks
  prefix_state<<<H, 1024, 0, stream>>>(S, KS);
  // 8) Wo -> transposed bf16 hi/lo
  wsplit_t<<<dim3(32, 32), 256, 0, stream>>>(Wo, WoTh, WoTl);
  // 9) fused chunk attention -> Ys hi/lo (overwrites A8 region, now dead)
  attn_chunk<<<dim3(NC, H), 256, 0, stream>>>(Qb, Kb, Vb, S, KS, Ah, Al);
  // 10) output projection (fully overwrites d_out, retiring KS scratch)
  gemm_split_bf16<<<dim3(16, 32), 256, 0, stream>>>(Ah, Al, WoTh, WoTl, out, L, D, H * HD);
}

// Round 8
// 133.625 us; speedup vs baseline: 2.4243x; 1.1293x over previous
//
#include <hip/hip_runtime.h>

// Problem constants (B=1)
constexpr int L  = 2048;
constexpr int D  = 1024;
constexpr int H  = 16;
constexpr int F  = 16;   // qk feature dim per head
constexpr int HD = 64;   // v head dim
constexpr int CHUNK = 128;
constexpr int NC = L / CHUNK;  // 16

typedef __bf16 bf16x8 __attribute__((ext_vector_type(8)));
typedef float  f32x16 __attribute__((ext_vector_type(16)));
typedef int    i32x4  __attribute__((ext_vector_type(4)));

__device__ __forceinline__ ushort f2bf(float f) {
  uint u = __builtin_bit_cast(uint, f);
  uint r = (u + 0x7FFFu + ((u >> 16) & 1u)) >> 16;
  return (ushort)r;
}
__device__ __forceinline__ float bf2f(ushort h) {
  uint u = ((uint)h) << 16;
  return __builtin_bit_cast(float, u);
}

// 5-slice signed-7-bit split of fp32 (scales 2^-4,2^-11,2^-18,2^-25,2^-32).
__device__ __forceinline__ void split5(float x, signed char s[5]) {
  float t = rintf(x * 16.f);              s[0] = (signed char)t;
  float r = fmaf(t, -6.25e-2f, x);
  t = rintf(r * 2048.f);                  s[1] = (signed char)t;
  r = fmaf(t, -4.8828125e-4f, r);
  t = rintf(r * 262144.f);                s[2] = (signed char)t;
  r = fmaf(t, -3.814697265625e-6f, r);
  t = rintf(r * 33554432.f);              s[3] = (signed char)t;
  r = fmaf(t, -2.9802322387695312e-8f, r);
  t = rintf(r * 4294967296.f);            s[4] = (signed char)t;
}

// ---------------------------------------------------------------------------
// hs fp32 -> Ah/Al bf16 hi/lo.  [proven]
// ---------------------------------------------------------------------------
__global__ __launch_bounds__(256) void split_hs(
    const float* __restrict__ X, ushort* __restrict__ Ah, ushort* __restrict__ Al) {
  int idx = blockIdx.x * 256 + threadIdx.x;
  if (idx >= L * D / 4) return;
  float4 v = ((const float4*)X)[idx];
  ushort4 h, l;
  h.x = f2bf(v.x); l.x = f2bf(v.x - bf2f(h.x));
  h.y = f2bf(v.y); l.y = f2bf(v.y - bf2f(h.y));
  h.z = f2bf(v.z); l.z = f2bf(v.z - bf2f(h.z));
  h.w = f2bf(v.w); l.w = f2bf(v.w - bf2f(h.w));
  ((ushort4*)Ah)[idx] = h;
  ((ushort4*)Al)[idx] = l;
}

// ---------------------------------------------------------------------------
// W[k][n] fp32 -> BTh/BTl[n][k] bf16 (transpose + split). [proven]
// ---------------------------------------------------------------------------
__global__ __launch_bounds__(256) void wsplit_t(
    const float* __restrict__ W, ushort* __restrict__ BTh, ushort* __restrict__ BTl) {
  __shared__ float t[32][33];
  const int tid = threadIdx.x;
  const int lx = tid & 31, ly = tid >> 5;
  const int bn = blockIdx.x * 32, bk = blockIdx.y * 32;
  #pragma unroll
  for (int i = 0; i < 32; i += 8)
    t[ly + i][lx] = W[(size_t)(bk + ly + i) * 1024 + bn + lx];
  __syncthreads();
  #pragma unroll
  for (int i = 0; i < 32; i += 8) {
    float v = t[lx][ly + i];
    ushort hh = f2bf(v);
    ushort ll = f2bf(v - bf2f(hh));
    size_t base = (size_t)(bn + ly + i) * 1024 + bk + lx;
    BTh[base] = hh;
    BTl[base] = ll;
  }
}

// ---------------------------------------------------------------------------
// hs -> 5 int8 slice planes A8[s][2048][1024].  [proven]
// ---------------------------------------------------------------------------
__global__ __launch_bounds__(256) void split_i8_hs(
    const float* __restrict__ X, signed char* __restrict__ A8) {
  const int plane = L * D;
  int idx = blockIdx.x * 256 + threadIdx.x;
  if (idx >= plane / 4) return;
  float4 v = ((const float4*)X)[idx];
  signed char sx[5], sy[5], sz[5], sw[5];
  split5(v.x, sx); split5(v.y, sy); split5(v.z, sz); split5(v.w, sw);
  #pragma unroll
  for (int s = 0; s < 5; ++s) {
    char4 c; c.x = sx[s]; c.y = sy[s]; c.z = sz[s]; c.w = sw[s];
    ((char4*)(A8 + (size_t)s * plane))[idx] = c;
  }
}

// ---------------------------------------------------------------------------
// [Wq|Wk] -> transposed 5-slice int8 W8[s][512][1024].  [proven]
// ---------------------------------------------------------------------------
__global__ __launch_bounds__(256) void wsplit_i8(
    const float* __restrict__ Wq, const float* __restrict__ Wk,
    signed char* __restrict__ W8) {
  const int plane = 512 * 1024;
  __shared__ float t[32][33];
  const int tid = threadIdx.x;
  const int lx = tid & 31, ly = tid >> 5;
  const int bn = blockIdx.x * 32, bk = blockIdx.y * 32;
  const float* W = (bn < 256) ? Wq : Wk;
  const int wn = bn & 255;
  #pragma unroll
  for (int i = 0; i < 32; i += 8)
    t[ly + i][lx] = W[(size_t)(bk + ly + i) * 256 + wn + lx];
  __syncthreads();
  #pragma unroll
  for (int i = 0; i < 32; i += 8) {
    float v = t[lx][ly + i];
    signed char s[5];
    split5(v, s);
    size_t base = (size_t)(bn + ly + i) * 1024 + bk + lx;
    #pragma unroll
    for (int si = 0; si < 5; ++si) W8[(size_t)si * plane + base] = s[si];
  }
}

// ---------------------------------------------------------------------------
// Exact QK projection via int8 MFMA (Ozaki 5-slice).  [proven round 7]
// ---------------------------------------------------------------------------
__global__ __launch_bounds__(512) void gemm_qk_i8(
    const signed char* __restrict__ A8, const signed char* __restrict__ W8,
    float* __restrict__ Qo, float* __restrict__ Ko) {
  constexpr int LDT = 80;
  __shared__ signed char As[5][64][LDT];
  __shared__ signed char Bs[5][64][LDT];
  const int aplane = L * D;
  const int bplane = 512 * 1024;
  const int tid  = threadIdx.x;
  const int wave = tid >> 6, lane = tid & 63;
  const int wm = (wave >> 2) * 32;
  const int wn = (wave & 3) * 16;
  const int brow = blockIdx.y * 64, bcol = blockIdx.x * 64;
  const int fr = lane & 15, kq = (lane >> 4) * 16;

  i32x4 acc[2][5];
  #pragma unroll
  for (int fm = 0; fm < 2; ++fm)
    #pragma unroll
    for (int g = 0; g < 5; ++g)
      #pragma unroll
      for (int r = 0; r < 4; ++r) acc[fm][g][r] = 0;

  for (int k0 = 0; k0 < D; k0 += 64) {
    #pragma unroll
    for (int i = 0; i < 5; ++i) {
      int c = i * 512 + tid;
      int side = (c >= 1280);
      int cc = side ? c - 1280 : c;
      int slice = cc >> 8, row = (cc & 255) >> 2, c16 = (cc & 3) * 16;
      const signed char* src = side
          ? &W8[(size_t)slice * bplane + (size_t)(bcol + row) * 1024 + k0 + c16]
          : &A8[(size_t)slice * aplane + (size_t)(brow + row) * 1024 + k0 + c16];
      int4 val = *(const int4*)src;
      signed char* dst = side ? &Bs[slice][row][c16] : &As[slice][row][c16];
      *(int4*)dst = val;
    }
    __syncthreads();
    i32x4 bfr[5], afr[2][5];
    #pragma unroll
    for (int s = 0; s < 5; ++s) bfr[s] = *(const i32x4*)&Bs[s][wn + fr][kq];
    #pragma unroll
    for (int fm = 0; fm < 2; ++fm)
      #pragma unroll
      for (int s = 0; s < 5; ++s)
        afr[fm][s] = *(const i32x4*)&As[s][wm + fm * 16 + fr][kq];
    #pragma unroll
    for (int fm = 0; fm < 2; ++fm) {
      acc[fm][0] = __builtin_amdgcn_mfma_i32_16x16x64_i8(afr[fm][0], bfr[0], acc[fm][0], 0, 0, 0);
      #pragma unroll
      for (int g = 1; g < 5; ++g)
        #pragma unroll
        for (int i = 0; i <= g; ++i)
          acc[fm][g] = __builtin_amdgcn_mfma_i32_16x16x64_i8(afr[fm][i], bfr[g - i], acc[fm][g], 0, 0, 0);
    }
    __syncthreads();
  }
  const double sc0 = 3.90625e-3, sc1 = 3.0517578125e-5, sc2 = 2.384185791015625e-7,
               sc3 = 1.862645149230957e-9, sc4 = 1.4551915228366852e-11;
  float* Out = (bcol < 256) ? Qo : Ko;
  const int ocol = (bcol & 255) + wn + fr;
  #pragma unroll
  for (int fm = 0; fm < 2; ++fm)
    #pragma unroll
    for (int r = 0; r < 4; ++r) {
      double v = (double)acc[fm][0][r] * sc0 + (double)acc[fm][1][r] * sc1 +
                 (double)acc[fm][2][r] * sc2 + (double)acc[fm][3][r] * sc3 +
                 (double)acc[fm][4][r] * sc4;
      int row = brow + wm + fm * 16 + (lane >> 4) * 4 + r;
      Out[(size_t)row * 256 + ocol] = (float)v;
    }
}

// ---------------------------------------------------------------------------
// bf16x2-split GEMM, double-buffered (round-2 fragment math verbatim;
// dbuf LOADT/WRITET pattern proven in rounds 4/5). One barrier per K-step.
// Tile 64x64, BK=32, 256 thr = 4 waves; grid (N/64, M/64).
// ---------------------------------------------------------------------------
__global__ __launch_bounds__(256) void gemm_split_bf16_db(
    const ushort* __restrict__ Ah, const ushort* __restrict__ Al,
    const ushort* __restrict__ BTh, const ushort* __restrict__ BTl,
    float* __restrict__ C, int M, int N, int K) {
  constexpr int LDT = 40;
  __shared__ __bf16 As[2][2][64][LDT];   // [buf][hi/lo][row][k]
  __shared__ __bf16 Bs[2][2][64][LDT];
  const int tid  = threadIdx.x;
  const int wave = tid >> 6, lane = tid & 63;
  const int wr = (wave >> 1) * 32, wc = (wave & 1) * 32;
  const int brow = blockIdx.y * 64, bcol = blockIdx.x * 64;
  const int srow = tid >> 2, skg = (tid & 3) * 8;
  const size_t a_off = (size_t)(brow + srow) * K + skg;
  const size_t b_off = (size_t)(bcol + srow) * K + skg;

  f32x16 acc;
  #pragma unroll
  for (int i = 0; i < 16; ++i) acc[i] = 0.f;

  bf16x8 rah, ral, rbh, rbl;
  auto LOADT = [&](int k0) {
    rah = *(const bf16x8*)&Ah[a_off + k0];
    ral = *(const bf16x8*)&Al[a_off + k0];
    rbh = *(const bf16x8*)&BTh[b_off + k0];
    rbl = *(const bf16x8*)&BTl[b_off + k0];
  };
  auto WRITET = [&](int buf) {
    *(bf16x8*)&As[buf][0][srow][skg] = rah;
    *(bf16x8*)&As[buf][1][srow][skg] = ral;
    *(bf16x8*)&Bs[buf][0][srow][skg] = rbh;
    *(bf16x8*)&Bs[buf][1][srow][skg] = rbl;
  };

  const int NS = K / 32;
  LOADT(0); WRITET(0);
  __syncthreads();
  int cur = 0;
  for (int t = 0; t < NS; ++t) {
    if (t + 1 < NS) LOADT((t + 1) * 32);
    const int fr = lane & 31;
    const int kh = (lane >> 5) * 8;
    bf16x8 ah0 = *(const bf16x8*)&As[cur][0][wr + fr][kh];
    bf16x8 ah1 = *(const bf16x8*)&As[cur][0][wr + fr][16 + kh];
    bf16x8 al0 = *(const bf16x8*)&As[cur][1][wr + fr][kh];
    bf16x8 al1 = *(const bf16x8*)&As[cur][1][wr + fr][16 + kh];
    bf16x8 bh0 = *(const bf16x8*)&Bs[cur][0][wc + fr][kh];
    bf16x8 bh1 = *(const bf16x8*)&Bs[cur][0][wc + fr][16 + kh];
    bf16x8 bl0 = *(const bf16x8*)&Bs[cur][1][wc + fr][kh];
    bf16x8 bl1 = *(const bf16x8*)&Bs[cur][1][wc + fr][16 + kh];
    acc = __builtin_amdgcn_mfma_f32_32x32x16_bf16(ah0, bh0, acc, 0, 0, 0);
    acc = __builtin_amdgcn_mfma_f32_32x32x16_bf16(ah1, bh1, acc, 0, 0, 0);
    acc = __builtin_amdgcn_mfma_f32_32x32x16_bf16(ah0, bl0, acc, 0, 0, 0);
    acc = __builtin_amdgcn_mfma_f32_32x32x16_bf16(ah1, bl1, acc, 0, 0, 0);
    acc = __builtin_amdgcn_mfma_f32_32x32x16_bf16(al0, bh0, acc, 0, 0, 0);
    acc = __builtin_amdgcn_mfma_f32_32x32x16_bf16(al1, bh1, acc, 0, 0, 0);
    if (t + 1 < NS) WRITET(cur ^ 1);
    __syncthreads();
    cur ^= 1;
  }
  const int fr = lane & 31, fq = lane >> 5;
  #pragma unroll
  for (int r = 0; r < 16; ++r) {
    int row = brow + wr + (r & 3) + 8 * (r >> 2) + 4 * fq;
    C[(size_t)row * N + bcol + wc + fr] = acc[r];
  }
}

// ---------------------------------------------------------------------------
// Per-chunk state sums  [proven]. Grid (NC, H), 256 threads.
// ---------------------------------------------------------------------------
__global__ __launch_bounds__(256) void chunk_state(
    const float* __restrict__ Kq, const float* __restrict__ V,
    float* __restrict__ S, double* __restrict__ KS) {
  const int c = blockIdx.x, h = blockIdx.y;
  __shared__ float Ks[CHUNK][F];
  __shared__ float Vs[CHUNK][HD];
  const int tid = threadIdx.x;
  #pragma unroll
  for (int i = 0; i < 2; ++i) {
    int g = i * 256 + tid;
    int m = g >> 2, f0 = (g & 3) * 4;
    *(float4*)&Ks[m][f0] = *(const float4*)&Kq[(size_t)(c * CHUNK + m) * (H * F) + h * F + f0];
  }
  #pragma unroll
  for (int i = 0; i < 8; ++i) {
    int g = i * 256 + tid;
    int m = g >> 4, e0 = (g & 15) * 4;
    *(float4*)&Vs[m][e0] = *(const float4*)&V[(size_t)(c * CHUNK + m) * (H * HD) + h * HD + e0];
  }
  __syncthreads();
  const int f = tid >> 4, e0 = (tid & 15) * 4;
  float4 acc = make_float4(0.f, 0.f, 0.f, 0.f);
  for (int m = 0; m < CHUNK; ++m) {
    float kv = Ks[m][f];
    float4 v4 = *(const float4*)&Vs[m][e0];
    acc.x = fmaf(kv, v4.x, acc.x);
    acc.y = fmaf(kv, v4.y, acc.y);
    acc.z = fmaf(kv, v4.z, acc.z);
    acc.w = fmaf(kv, v4.w, acc.w);
  }
  *(float4*)&S[((((size_t)h * NC) + c) * F + f) * HD + e0] = acc;
  if (tid < F) {
    double s = 0.0;
    for (int m = 0; m < CHUNK; ++m) s += (double)Ks[m][tid];
    KS[(((size_t)h * NC) + c) * F + tid] = s;
  }
}

// ---------------------------------------------------------------------------
// In-place exclusive prefix over chunks  [proven]. Grid H.
// ---------------------------------------------------------------------------
__global__ void prefix_state(float* __restrict__ S, double* __restrict__ KS) {
  const int h = blockIdx.x;
  const int tid = threadIdx.x;
  float run = 0.f;
  for (int c = 0; c < NC; ++c) {
    size_t idx = (((size_t)h * NC) + c) * (F * HD) + tid;
    float v = S[idx];
    S[idx] = run;
    run += v;
  }
  if (tid < F) {
    double rk = 0.0;
    for (int c = 0; c < NC; ++c) {
      size_t idx = (((size_t)h * NC) + c) * F + tid;
      double v = KS[idx];
      KS[idx] = rk;
      rk += v;
    }
  }
}

// ---------------------------------------------------------------------------
// Fused chunk attention v2: 512 threads (8 waves -> 2/SIMD), micro 2 rows x
// 8 cols. Same math as proven v1; staging rescaled; wave-uniform causal
// early-exit at 16-row granularity. Grid (NC, H).
// ---------------------------------------------------------------------------
__global__ __launch_bounds__(512) void attn_chunk_v2(
    const float* __restrict__ Q, const float* __restrict__ Kq, const float* __restrict__ V,
    const float* __restrict__ Sin, const double* __restrict__ kcum,
    ushort* __restrict__ Yh, ushort* __restrict__ Yl) {
  const int c = blockIdx.x, h = blockIdx.y;
  __shared__ float Ks[CHUNK][F];
  __shared__ float Vs[CHUNK][HD];
  __shared__ float Ss[F][HD];
  __shared__ double kcs[F];
  __shared__ float zs[CHUNK];
  const int tid = threadIdx.x;

  {  // Ks: 512 float4, 1/thread
    int m = tid >> 2, f0 = (tid & 3) * 4;
    *(float4*)&Ks[m][f0] = *(const float4*)&Kq[(size_t)(c * CHUNK + m) * (H * F) + h * F + f0];
  }
  #pragma unroll
  for (int i = 0; i < 4; ++i) {  // Vs: 2048 float4, 4/thread
    int g = i * 512 + tid;
    int m = g >> 4, e0 = (g & 15) * 4;
    *(float4*)&Vs[m][e0] = *(const float4*)&V[(size_t)(c * CHUNK + m) * (H * HD) + h * HD + e0];
  }
  if (tid < 256) {  // Ss: 256 float4
    int f = tid >> 4, e0 = (tid & 15) * 4;
    *(float4*)&Ss[f][e0] = *(const float4*)&Sin[(((size_t)h * NC) + c) * (F * HD) + f * HD + e0];
  }
  if (tid < F) kcs[tid] = kcum[(((size_t)h * NC) + c) * F + tid];
  __syncthreads();

  const int rg = tid >> 3;      // 0..63
  const int cg = tid & 7;       // 0..7
  const int i0 = rg * 2;        // rows i0, i0+1
  const int e0 = cg * 8;

  float q[2][F];
  #pragma unroll
  for (int r = 0; r < 2; ++r)
    #pragma unroll
    for (int f0 = 0; f0 < F; f0 += 4)
      *(float4*)&q[r][f0] = *(const float4*)&Q[(size_t)(c * CHUNK + i0 + r) * (H * F) + h * F + f0];

  float acc[2][8];
  #pragma unroll
  for (int r = 0; r < 2; ++r)
    #pragma unroll
    for (int j = 0; j < 8; ++j) acc[r][j] = 0.f;
  float den[2] = {0.f, 0.f};

  const int mmax = ((tid >> 6) + 1) * 16;   // wave-uniform causal bound
  for (int m = 0; m < mmax; ++m) {
    float kr[F];
    #pragma unroll
    for (int f0 = 0; f0 < F; f0 += 4)
      *(float4*)&kr[f0] = *(const float4*)&Ks[m][f0];
    float a[2];
    #pragma unroll
    for (int r = 0; r < 2; ++r) {
      float s = 0.f;
      #pragma unroll
      for (int f = 0; f < F; ++f) s = fmaf(q[r][f], kr[f], s);
      a[r] = (m <= i0 + r) ? s : 0.f;
      den[r] += a[r];
    }
    float v8[8];
    *(float4*)&v8[0] = *(const float4*)&Vs[m][e0];
    *(float4*)&v8[4] = *(const float4*)&Vs[m][e0 + 4];
    #pragma unroll
    for (int r = 0; r < 2; ++r)
      #pragma unroll
      for (int j = 0; j < 8; ++j)
        acc[r][j] = fmaf(a[r], v8[j], acc[r][j]);
  }

  #pragma unroll
  for (int f = 0; f < F; ++f) {
    float s8[8];
    *(float4*)&s8[0] = *(const float4*)&Ss[f][e0];
    *(float4*)&s8[4] = *(const float4*)&Ss[f][e0 + 4];
    #pragma unroll
    for (int r = 0; r < 2; ++r)
      #pragma unroll
      for (int j = 0; j < 8; ++j)
        acc[r][j] = fmaf(q[r][f], s8[j], acc[r][j]);
  }

  if (cg == 0) {
    #pragma unroll
    for (int r = 0; r < 2; ++r) {
      double dd = (double)den[r];
      #pragma unroll
      for (int f = 0; f < F; ++f) dd += (double)q[r][f] * kcs[f];
      zs[i0 + r] = (float)(1.0 / (dd + 1e-12));
    }
  }
  __syncthreads();

  #pragma unroll
  for (int r = 0; r < 2; ++r) {
    float zz = zs[i0 + r];
    ushort4 h4a, h4b, l4a, l4b;
    float o;
    o = acc[r][0] * zz; h4a.x = f2bf(o); l4a.x = f2bf(o - bf2f(h4a.x));
    o = acc[r][1] * zz; h4a.y = f2bf(o); l4a.y = f2bf(o - bf2f(h4a.y));
    o = acc[r][2] * zz; h4a.z = f2bf(o); l4a.z = f2bf(o - bf2f(h4a.z));
    o = acc[r][3] * zz; h4a.w = f2bf(o); l4a.w = f2bf(o - bf2f(h4a.w));
    o = acc[r][4] * zz; h4b.x = f2bf(o); l4b.x = f2bf(o - bf2f(h4b.x));
    o = acc[r][5] * zz; h4b.y = f2bf(o); l4b.y = f2bf(o - bf2f(h4b.y));
    o = acc[r][6] * zz; h4b.z = f2bf(o); l4b.z = f2bf(o - bf2f(h4b.z));
    o = acc[r][7] * zz; h4b.w = f2bf(o); l4b.w = f2bf(o - bf2f(h4b.w));
    size_t base = (size_t)(c * CHUNK + i0 + r) * 1024 + h * HD + e0;
    *(ushort4*)&Yh[base]     = h4a;
    *(ushort4*)&Yh[base + 4] = h4b;
    *(ushort4*)&Yl[base]     = l4a;
    *(ushort4*)&Yl[base + 4] = l4b;
  }
}

// ---------------------------------------------------------------------------
extern "C" void kernel_launch(void* const* d_in, const int* in_sizes, int n_in,
                              void* d_out, int out_size, void* d_ws, size_t ws_size,
                              hipStream_t stream) {
  const float* hs = (const float*)d_in[0];
  const float* Wq = (const float*)d_in[1];
  const float* Wk = (const float*)d_in[2];
  const float* Wv = (const float*)d_in[3];
  const float* Wo = (const float*)d_in[4];
  float* out = (float*)d_out;

  char* ws = (char*)d_ws;
  const size_t MB = 1 << 20;
  ushort* Ah   = (ushort*)(ws + 0 * MB);        // 4 MB hs_hi -> later Ys_hi
  ushort* Al   = (ushort*)(ws + 4 * MB);        // 4 MB hs_lo -> later Ys_lo
  ushort* Bh   = (ushort*)(ws + 8 * MB);        // 2 MB WvT_hi
  ushort* Bl   = (ushort*)(ws + 10 * MB);       // 2 MB WvT_lo
  signed char* A8 = (signed char*)(ws + 0 * MB);   // 10 MB (overlays Ah/Al/Bh after V-GEMM)
  signed char* W8 = (signed char*)(ws + 10 * MB);  // 2.5 MB (overlays Bl)
  float*  Vb   = (float*)(ws + 13 * MB);        // 8 MB
  float*  Qb   = (float*)(ws + 21 * MB);        // 2 MB
  float*  Kb   = (float*)(ws + 23 * MB);        // 2 MB
  float*  S    = (float*)(ws + 25 * MB);        // 1 MB
  ushort* WoTh = (ushort*)(ws + 26 * MB);       // 2 MB
  ushort* WoTl = (ushort*)(ws + 28 * MB);       // 2 MB  (peak 30 MB)
  double* KS   = (double*)d_out;                // 32 KB scratch, retired by step 10

  // 1) hs -> bf16 hi/lo
  split_hs<<<dim3(L * D / 4 / 256), 256, 0, stream>>>(hs, Ah, Al);
  // 2) Wv -> transposed bf16 hi/lo
  wsplit_t<<<dim3(32, 32), 256, 0, stream>>>(Wv, Bh, Bl);
  // 3) V projection (double-buffered split GEMM)
  gemm_split_bf16_db<<<dim3(16, 32), 256, 0, stream>>>(Ah, Al, Bh, Bl, Vb, L, 1024, D);
  // 4) int8 5-slice splits (overwrite hs/Wv split buffers, now dead)
  split_i8_hs<<<dim3(L * D / 4 / 256), 256, 0, stream>>>(hs, A8);
  wsplit_i8<<<dim3(16, 32), 256, 0, stream>>>(Wq, Wk, W8);
  // 5) exact QK projection via i8 MFMA
  gemm_qk_i8<<<dim3(8, 32), 512, 0, stream>>>(A8, W8, Qb, Kb);
  // 6) per-chunk k^T v states + fp64 k sums
  chunk_state<<<dim3(NC, H), 256, 0, stream>>>(Kb, Vb, S, KS);
  // 7) in-place exclusive prefix over chunks
  prefix_state<<<H, 1024, 0, stream>>>(S, KS);
  // 8) Wo -> transposed bf16 hi/lo
  wsplit_t<<<dim3(32, 32), 256, 0, stream>>>(Wo, WoTh, WoTl);
  // 9) fused chunk attention v2 (8 waves) -> Ys hi/lo
  attn_chunk_v2<<<dim3(NC, H), 512, 0, stream>>>(Qb, Kb, Vb, S, KS, Ah, Al);
  // 10) output projection (fully overwrites d_out, retiring KS scratch)
  gemm_split_bf16_db<<<dim3(16, 32), 256, 0, stream>>>(Ah, Al, WoTh, WoTl, out, L, D, H * HD);
}

// Round 9
// 123.532 us; speedup vs baseline: 2.6224x; 1.0817x over previous
//
#include <hip/hip_runtime.h>

// Problem constants (B=1)
constexpr int L  = 2048;
constexpr int D  = 1024;
constexpr int H  = 16;
constexpr int F  = 16;   // qk feature dim per head
constexpr int HD = 64;   // v head dim
constexpr int CHUNK = 128;
constexpr int NC = L / CHUNK;  // 16

typedef __bf16 bf16x8 __attribute__((ext_vector_type(8)));
typedef float  f32x16 __attribute__((ext_vector_type(16)));
typedef int    i32x4  __attribute__((ext_vector_type(4)));

__device__ __forceinline__ ushort f2bf(float f) {
  uint u = __builtin_bit_cast(uint, f);
  uint r = (u + 0x7FFFu + ((u >> 16) & 1u)) >> 16;
  return (ushort)r;
}
__device__ __forceinline__ float bf2f(ushort h) {
  uint u = ((uint)h) << 16;
  return __builtin_bit_cast(float, u);
}

// 5-slice signed-7-bit split of fp32 (scales 2^-4,2^-11,2^-18,2^-25,2^-32).
__device__ __forceinline__ void split5(float x, signed char s[5]) {
  float t = rintf(x * 16.f);              s[0] = (signed char)t;
  float r = fmaf(t, -6.25e-2f, x);
  t = rintf(r * 2048.f);                  s[1] = (signed char)t;
  r = fmaf(t, -4.8828125e-4f, r);
  t = rintf(r * 262144.f);                s[2] = (signed char)t;
  r = fmaf(t, -3.814697265625e-6f, r);
  t = rintf(r * 33554432.f);              s[3] = (signed char)t;
  r = fmaf(t, -2.9802322387695312e-8f, r);
  t = rintf(r * 4294967296.f);            s[4] = (signed char)t;
}

// ---------------------------------------------------------------------------
// hs fp32 -> Ah/Al bf16 hi/lo.  [proven]
// ---------------------------------------------------------------------------
__global__ __launch_bounds__(256) void split_hs(
    const float* __restrict__ X, ushort* __restrict__ Ah, ushort* __restrict__ Al) {
  int idx = blockIdx.x * 256 + threadIdx.x;
  if (idx >= L * D / 4) return;
  float4 v = ((const float4*)X)[idx];
  ushort4 h, l;
  h.x = f2bf(v.x); l.x = f2bf(v.x - bf2f(h.x));
  h.y = f2bf(v.y); l.y = f2bf(v.y - bf2f(h.y));
  h.z = f2bf(v.z); l.z = f2bf(v.z - bf2f(h.z));
  h.w = f2bf(v.w); l.w = f2bf(v.w - bf2f(h.w));
  ((ushort4*)Ah)[idx] = h;
  ((ushort4*)Al)[idx] = l;
}

// ---------------------------------------------------------------------------
// Fused weight transpose+split: z=0: Wv -> B0h/B0l ; z=1: Wo -> B1h/B1l.
// Grid (32,32,2).  [round-2 z-pattern + proven body]
// ---------------------------------------------------------------------------
__global__ __launch_bounds__(256) void wsplit_t2(
    const float* __restrict__ W0, const float* __restrict__ W1,
    ushort* __restrict__ B0h, ushort* __restrict__ B0l,
    ushort* __restrict__ B1h, ushort* __restrict__ B1l) {
  const float* W = blockIdx.z ? W1 : W0;
  ushort* BTh = blockIdx.z ? B1h : B0h;
  ushort* BTl = blockIdx.z ? B1l : B0l;
  __shared__ float t[32][33];
  const int tid = threadIdx.x;
  const int lx = tid & 31, ly = tid >> 5;
  const int bn = blockIdx.x * 32, bk = blockIdx.y * 32;
  #pragma unroll
  for (int i = 0; i < 32; i += 8)
    t[ly + i][lx] = W[(size_t)(bk + ly + i) * 1024 + bn + lx];
  __syncthreads();
  #pragma unroll
  for (int i = 0; i < 32; i += 8) {
    float v = t[lx][ly + i];
    ushort hh = f2bf(v);
    ushort ll = f2bf(v - bf2f(hh));
    size_t base = (size_t)(bn + ly + i) * 1024 + bk + lx;
    BTh[base] = hh;
    BTl[base] = ll;
  }
}

// ---------------------------------------------------------------------------
// hs -> 5 int8 slice planes A8[s][2048][1024].  [proven]
// ---------------------------------------------------------------------------
__global__ __launch_bounds__(256) void split_i8_hs(
    const float* __restrict__ X, signed char* __restrict__ A8) {
  const int plane = L * D;
  int idx = blockIdx.x * 256 + threadIdx.x;
  if (idx >= plane / 4) return;
  float4 v = ((const float4*)X)[idx];
  signed char sx[5], sy[5], sz[5], sw[5];
  split5(v.x, sx); split5(v.y, sy); split5(v.z, sz); split5(v.w, sw);
  #pragma unroll
  for (int s = 0; s < 5; ++s) {
    char4 c; c.x = sx[s]; c.y = sy[s]; c.z = sz[s]; c.w = sw[s];
    ((char4*)(A8 + (size_t)s * plane))[idx] = c;
  }
}

// ---------------------------------------------------------------------------
// [Wq|Wk] -> transposed 5-slice int8 W8[s][512][1024].  [proven]
// ---------------------------------------------------------------------------
__global__ __launch_bounds__(256) void wsplit_i8(
    const float* __restrict__ Wq, const float* __restrict__ Wk,
    signed char* __restrict__ W8) {
  const int plane = 512 * 1024;
  __shared__ float t[32][33];
  const int tid = threadIdx.x;
  const int lx = tid & 31, ly = tid >> 5;
  const int bn = blockIdx.x * 32, bk = blockIdx.y * 32;
  const float* W = (bn < 256) ? Wq : Wk;
  const int wn = bn & 255;
  #pragma unroll
  for (int i = 0; i < 32; i += 8)
    t[ly + i][lx] = W[(size_t)(bk + ly + i) * 256 + wn + lx];
  __syncthreads();
  #pragma unroll
  for (int i = 0; i < 32; i += 8) {
    float v = t[lx][ly + i];
    signed char s[5];
    split5(v, s);
    size_t base = (size_t)(bn + ly + i) * 1024 + bk + lx;
    #pragma unroll
    for (int si = 0; si < 5; ++si) W8[(size_t)si * plane + base] = s[si];
  }
}

// ---------------------------------------------------------------------------
// Exact QK projection via int8 MFMA (Ozaki 5-slice).  [proven round 7]
// + XCD-aware bijective swizzle (grid 256 = 8*32, %8==0).
// ---------------------------------------------------------------------------
__global__ __launch_bounds__(512) void gemm_qk_i8(
    const signed char* __restrict__ A8, const signed char* __restrict__ W8,
    float* __restrict__ Qo, float* __restrict__ Ko) {
  constexpr int LDT = 80;
  __shared__ signed char As[5][64][LDT];
  __shared__ signed char Bs[5][64][LDT];
  const int aplane = L * D;
  const int bplane = 512 * 1024;
  const int tid  = threadIdx.x;
  const int wave = tid >> 6, lane = tid & 63;
  const int wm = (wave >> 2) * 32;
  const int wn = (wave & 3) * 16;
  // XCD swizzle
  const int nbx = gridDim.x, nwg = gridDim.x * gridDim.y;
  int bid = blockIdx.y * nbx + blockIdx.x;
  bid = (bid & 7) * (nwg >> 3) + (bid >> 3);
  const int brow = (bid / nbx) * 64, bcol = (bid % nbx) * 64;
  const int fr = lane & 15, kq = (lane >> 4) * 16;

  i32x4 acc[2][5];
  #pragma unroll
  for (int fm = 0; fm < 2; ++fm)
    #pragma unroll
    for (int g = 0; g < 5; ++g)
      #pragma unroll
      for (int r = 0; r < 4; ++r) acc[fm][g][r] = 0;

  for (int k0 = 0; k0 < D; k0 += 64) {
    #pragma unroll
    for (int i = 0; i < 5; ++i) {
      int c = i * 512 + tid;
      int side = (c >= 1280);
      int cc = side ? c - 1280 : c;
      int slice = cc >> 8, row = (cc & 255) >> 2, c16 = (cc & 3) * 16;
      const signed char* src = side
          ? &W8[(size_t)slice * bplane + (size_t)(bcol + row) * 1024 + k0 + c16]
          : &A8[(size_t)slice * aplane + (size_t)(brow + row) * 1024 + k0 + c16];
      int4 val = *(const int4*)src;
      signed char* dst = side ? &Bs[slice][row][c16] : &As[slice][row][c16];
      *(int4*)dst = val;
    }
    __syncthreads();
    i32x4 bfr[5], afr[2][5];
    #pragma unroll
    for (int s = 0; s < 5; ++s) bfr[s] = *(const i32x4*)&Bs[s][wn + fr][kq];
    #pragma unroll
    for (int fm = 0; fm < 2; ++fm)
      #pragma unroll
      for (int s = 0; s < 5; ++s)
        afr[fm][s] = *(const i32x4*)&As[s][wm + fm * 16 + fr][kq];
    #pragma unroll
    for (int fm = 0; fm < 2; ++fm) {
      acc[fm][0] = __builtin_amdgcn_mfma_i32_16x16x64_i8(afr[fm][0], bfr[0], acc[fm][0], 0, 0, 0);
      #pragma unroll
      for (int g = 1; g < 5; ++g)
        #pragma unroll
        for (int i = 0; i <= g; ++i)
          acc[fm][g] = __builtin_amdgcn_mfma_i32_16x16x64_i8(afr[fm][i], bfr[g - i], acc[fm][g], 0, 0, 0);
    }
    __syncthreads();
  }
  const double sc0 = 3.90625e-3, sc1 = 3.0517578125e-5, sc2 = 2.384185791015625e-7,
               sc3 = 1.862645149230957e-9, sc4 = 1.4551915228366852e-11;
  float* Out = (bcol < 256) ? Qo : Ko;
  const int ocol = (bcol & 255) + wn + fr;
  #pragma unroll
  for (int fm = 0; fm < 2; ++fm)
    #pragma unroll
    for (int r = 0; r < 4; ++r) {
      double v = (double)acc[fm][0][r] * sc0 + (double)acc[fm][1][r] * sc1 +
                 (double)acc[fm][2][r] * sc2 + (double)acc[fm][3][r] * sc3 +
                 (double)acc[fm][4][r] * sc4;
      int row = brow + wm + fm * 16 + (lane >> 4) * 4 + r;
      Out[(size_t)row * 256 + ocol] = (float)v;
    }
}

// ---------------------------------------------------------------------------
// bf16x2-split GEMM, double-buffered  [proven round 8] + XCD swizzle
// (grid 512 = 16*32, %8==0). Tile 64x64, BK=32, 4 waves.
// ---------------------------------------------------------------------------
__global__ __launch_bounds__(256) void gemm_split_bf16_db(
    const ushort* __restrict__ Ah, const ushort* __restrict__ Al,
    const ushort* __restrict__ BTh, const ushort* __restrict__ BTl,
    float* __restrict__ C, int M, int N, int K) {
  constexpr int LDT = 40;
  __shared__ __bf16 As[2][2][64][LDT];   // [buf][hi/lo][row][k]
  __shared__ __bf16 Bs[2][2][64][LDT];
  const int tid  = threadIdx.x;
  const int wave = tid >> 6, lane = tid & 63;
  const int wr = (wave >> 1) * 32, wc = (wave & 1) * 32;
  // XCD swizzle
  const int nbx = gridDim.x, nwg = gridDim.x * gridDim.y;
  int bid = blockIdx.y * nbx + blockIdx.x;
  bid = (bid & 7) * (nwg >> 3) + (bid >> 3);
  const int brow = (bid / nbx) * 64, bcol = (bid % nbx) * 64;
  const int srow = tid >> 2, skg = (tid & 3) * 8;
  const size_t a_off = (size_t)(brow + srow) * K + skg;
  const size_t b_off = (size_t)(bcol + srow) * K + skg;

  f32x16 acc;
  #pragma unroll
  for (int i = 0; i < 16; ++i) acc[i] = 0.f;

  bf16x8 rah, ral, rbh, rbl;
  auto LOADT = [&](int k0) {
    rah = *(const bf16x8*)&Ah[a_off + k0];
    ral = *(const bf16x8*)&Al[a_off + k0];
    rbh = *(const bf16x8*)&BTh[b_off + k0];
    rbl = *(const bf16x8*)&BTl[b_off + k0];
  };
  auto WRITET = [&](int buf) {
    *(bf16x8*)&As[buf][0][srow][skg] = rah;
    *(bf16x8*)&As[buf][1][srow][skg] = ral;
    *(bf16x8*)&Bs[buf][0][srow][skg] = rbh;
    *(bf16x8*)&Bs[buf][1][srow][skg] = rbl;
  };

  const int NS = K / 32;
  LOADT(0); WRITET(0);
  __syncthreads();
  int cur = 0;
  for (int t = 0; t < NS; ++t) {
    if (t + 1 < NS) LOADT((t + 1) * 32);
    const int fr = lane & 31;
    const int kh = (lane >> 5) * 8;
    bf16x8 ah0 = *(const bf16x8*)&As[cur][0][wr + fr][kh];
    bf16x8 ah1 = *(const bf16x8*)&As[cur][0][wr + fr][16 + kh];
    bf16x8 al0 = *(const bf16x8*)&As[cur][1][wr + fr][kh];
    bf16x8 al1 = *(const bf16x8*)&As[cur][1][wr + fr][16 + kh];
    bf16x8 bh0 = *(const bf16x8*)&Bs[cur][0][wc + fr][kh];
    bf16x8 bh1 = *(const bf16x8*)&Bs[cur][0][wc + fr][16 + kh];
    bf16x8 bl0 = *(const bf16x8*)&Bs[cur][1][wc + fr][kh];
    bf16x8 bl1 = *(const bf16x8*)&Bs[cur][1][wc + fr][16 + kh];
    acc = __builtin_amdgcn_mfma_f32_32x32x16_bf16(ah0, bh0, acc, 0, 0, 0);
    acc = __builtin_amdgcn_mfma_f32_32x32x16_bf16(ah1, bh1, acc, 0, 0, 0);
    acc = __builtin_amdgcn_mfma_f32_32x32x16_bf16(ah0, bl0, acc, 0, 0, 0);
    acc = __builtin_amdgcn_mfma_f32_32x32x16_bf16(ah1, bl1, acc, 0, 0, 0);
    acc = __builtin_amdgcn_mfma_f32_32x32x16_bf16(al0, bh0, acc, 0, 0, 0);
    acc = __builtin_amdgcn_mfma_f32_32x32x16_bf16(al1, bh1, acc, 0, 0, 0);
    if (t + 1 < NS) WRITET(cur ^ 1);
    __syncthreads();
    cur ^= 1;
  }
  const int fr = lane & 31, fq = lane >> 5;
  #pragma unroll
  for (int r = 0; r < 16; ++r) {
    int row = brow + wr + (r & 3) + 8 * (r >> 2) + 4 * fq;
    C[(size_t)row * N + bcol + wc + fr] = acc[r];
  }
}

// ---------------------------------------------------------------------------
// Per-chunk state sums  [proven]. Grid (NC, H), 256 threads.
// ---------------------------------------------------------------------------
__global__ __launch_bounds__(256) void chunk_state(
    const float* __restrict__ Kq, const float* __restrict__ V,
    float* __restrict__ S, double* __restrict__ KS) {
  const int c = blockIdx.x, h = blockIdx.y;
  __shared__ float Ks[CHUNK][F];
  __shared__ float Vs[CHUNK][HD];
  const int tid = threadIdx.x;
  #pragma unroll
  for (int i = 0; i < 2; ++i) {
    int g = i * 256 + tid;
    int m = g >> 2, f0 = (g & 3) * 4;
    *(float4*)&Ks[m][f0] = *(const float4*)&Kq[(size_t)(c * CHUNK + m) * (H * F) + h * F + f0];
  }
  #pragma unroll
  for (int i = 0; i < 8; ++i) {
    int g = i * 256 + tid;
    int m = g >> 4, e0 = (g & 15) * 4;
    *(float4*)&Vs[m][e0] = *(const float4*)&V[(size_t)(c * CHUNK + m) * (H * HD) + h * HD + e0];
  }
  __syncthreads();
  const int f = tid >> 4, e0 = (tid & 15) * 4;
  float4 acc = make_float4(0.f, 0.f, 0.f, 0.f);
  for (int m = 0; m < CHUNK; ++m) {
    float kv = Ks[m][f];
    float4 v4 = *(const float4*)&Vs[m][e0];
    acc.x = fmaf(kv, v4.x, acc.x);
    acc.y = fmaf(kv, v4.y, acc.y);
    acc.z = fmaf(kv, v4.z, acc.z);
    acc.w = fmaf(kv, v4.w, acc.w);
  }
  *(float4*)&S[((((size_t)h * NC) + c) * F + f) * HD + e0] = acc;
  if (tid < F) {
    double s = 0.0;
    for (int m = 0; m < CHUNK; ++m) s += (double)Ks[m][tid];
    KS[(((size_t)h * NC) + c) * F + tid] = s;
  }
}

// ---------------------------------------------------------------------------
// In-place exclusive prefix over chunks  [proven]. Grid H.
// ---------------------------------------------------------------------------
__global__ void prefix_state(float* __restrict__ S, double* __restrict__ KS) {
  const int h = blockIdx.x;
  const int tid = threadIdx.x;
  float run = 0.f;
  for (int c = 0; c < NC; ++c) {
    size_t idx = (((size_t)h * NC) + c) * (F * HD) + tid;
    float v = S[idx];
    S[idx] = run;
    run += v;
  }
  if (tid < F) {
    double rk = 0.0;
    for (int c = 0; c < NC; ++c) {
      size_t idx = (((size_t)h * NC) + c) * F + tid;
      double v = KS[idx];
      KS[idx] = rk;
      rk += v;
    }
  }
}

// ---------------------------------------------------------------------------
// Fused chunk attention v3: balanced causal pairing. 512 thr = 8 waves;
// wave w owns low rows 8w..8w+7 AND high rows 120-8w..127-8w (const work).
// Merged m-loop (bound 128-8w, low-row update under wave-uniform m<m1) so
// each kr/v8 is loaded once per iter. Same math as proven v1/v2. Grid (NC,H).
// ---------------------------------------------------------------------------
__global__ __launch_bounds__(512) void attn_chunk_v3(
    const float* __restrict__ Q, const float* __restrict__ Kq, const float* __restrict__ V,
    const float* __restrict__ Sin, const double* __restrict__ kcum,
    ushort* __restrict__ Yh, ushort* __restrict__ Yl) {
  const int c = blockIdx.x, h = blockIdx.y;
  __shared__ float Ks[CHUNK][F];
  __shared__ float Vs[CHUNK][HD];
  __shared__ float Ss[F][HD];
  __shared__ double kcs[F];
  __shared__ float zs[CHUNK];
  const int tid = threadIdx.x;

  {  // Ks: 512 float4, 1/thread
    int m = tid >> 2, f0 = (tid & 3) * 4;
    *(float4*)&Ks[m][f0] = *(const float4*)&Kq[(size_t)(c * CHUNK + m) * (H * F) + h * F + f0];
  }
  #pragma unroll
  for (int i = 0; i < 4; ++i) {  // Vs: 2048 float4, 4/thread
    int g = i * 512 + tid;
    int m = g >> 4, e0 = (g & 15) * 4;
    *(float4*)&Vs[m][e0] = *(const float4*)&V[(size_t)(c * CHUNK + m) * (H * HD) + h * HD + e0];
  }
  if (tid < 256) {  // Ss: 256 float4
    int f = tid >> 4, e0 = (tid & 15) * 4;
    *(float4*)&Ss[f][e0] = *(const float4*)&Sin[(((size_t)h * NC) + c) * (F * HD) + f * HD + e0];
  }
  if (tid < F) kcs[tid] = kcum[(((size_t)h * NC) + c) * F + tid];
  __syncthreads();

  const int w = tid >> 6;        // wave 0..7
  const int lane = tid & 63;
  const int rsub = lane >> 3;    // 0..7
  const int cg = lane & 7;
  const int e0 = cg * 8;
  const int lr = 8 * w + rsub;          // low row
  const int hr = 120 - 8 * w + rsub;    // high row

  float ql[F], qh[F];
  #pragma unroll
  for (int f0 = 0; f0 < F; f0 += 4) {
    *(float4*)&ql[f0] = *(const float4*)&Q[(size_t)(c * CHUNK + lr) * (H * F) + h * F + f0];
    *(float4*)&qh[f0] = *(const float4*)&Q[(size_t)(c * CHUNK + hr) * (H * F) + h * F + f0];
  }

  float accl[8], acch[8];
  #pragma unroll
  for (int j = 0; j < 8; ++j) { accl[j] = 0.f; acch[j] = 0.f; }
  float denl = 0.f, denh = 0.f;

  const int m1 = 8 * w + 8;      // wave-uniform: low rows need m < m1
  const int m2 = 128 - 8 * w;    // wave-uniform: high rows need m < m2 (>= m1)
  for (int m = 0; m < m2; ++m) {
    float kr[F];
    #pragma unroll
    for (int f0 = 0; f0 < F; f0 += 4)
      *(float4*)&kr[f0] = *(const float4*)&Ks[m][f0];
    float v8[8];
    *(float4*)&v8[0] = *(const float4*)&Vs[m][e0];
    *(float4*)&v8[4] = *(const float4*)&Vs[m][e0 + 4];
    {
      float s = 0.f;
      #pragma unroll
      for (int f = 0; f < F; ++f) s = fmaf(qh[f], kr[f], s);
      float a = (m <= hr) ? s : 0.f;
      denh += a;
      #pragma unroll
      for (int j = 0; j < 8; ++j) acch[j] = fmaf(a, v8[j], acch[j]);
    }
    if (m < m1) {   // wave-uniform branch
      float s = 0.f;
      #pragma unroll
      for (int f = 0; f < F; ++f) s = fmaf(ql[f], kr[f], s);
      float a = (m <= lr) ? s : 0.f;
      denl += a;
      #pragma unroll
      for (int j = 0; j < 8; ++j) accl[j] = fmaf(a, v8[j], accl[j]);
    }
  }

  // inter-chunk numerator: q @ Sin (both rows)
  #pragma unroll
  for (int f = 0; f < F; ++f) {
    float s8[8];
    *(float4*)&s8[0] = *(const float4*)&Ss[f][e0];
    *(float4*)&s8[4] = *(const float4*)&Ss[f][e0 + 4];
    #pragma unroll
    for (int j = 0; j < 8; ++j) {
      accl[j] = fmaf(ql[f], s8[j], accl[j]);
      acch[j] = fmaf(qh[f], s8[j], acch[j]);
    }
  }

  if (cg == 0) {
    double dl = (double)denl, dh = (double)denh;
    #pragma unroll
    for (int f = 0; f < F; ++f) {
      dl += (double)ql[f] * kcs[f];
      dh += (double)qh[f] * kcs[f];
    }
    zs[lr] = (float)(1.0 / (dl + 1e-12));
    zs[hr] = (float)(1.0 / (dh + 1e-12));
  }
  __syncthreads();

  #pragma unroll
  for (int rr = 0; rr < 2; ++rr) {
    const int row = rr ? hr : lr;
    const float* ac = rr ? acch : accl;
    float zz = zs[row];
    ushort4 h4a, h4b, l4a, l4b;
    float o;
    o = ac[0] * zz; h4a.x = f2bf(o); l4a.x = f2bf(o - bf2f(h4a.x));
    o = ac[1] * zz; h4a.y = f2bf(o); l4a.y = f2bf(o - bf2f(h4a.y));
    o = ac[2] * zz; h4a.z = f2bf(o); l4a.z = f2bf(o - bf2f(h4a.z));
    o = ac[3] * zz; h4a.w = f2bf(o); l4a.w = f2bf(o - bf2f(h4a.w));
    o = ac[4] * zz; h4b.x = f2bf(o); l4b.x = f2bf(o - bf2f(h4b.x));
    o = ac[5] * zz; h4b.y = f2bf(o); l4b.y = f2bf(o - bf2f(h4b.y));
    o = ac[6] * zz; h4b.z = f2bf(o); l4b.z = f2bf(o - bf2f(h4b.z));
    o = ac[7] * zz; h4b.w = f2bf(o); l4b.w = f2bf(o - bf2f(h4b.w));
    size_t base = (size_t)(c * CHUNK + row) * 1024 + h * HD + e0;
    *(ushort4*)&Yh[base]     = h4a;
    *(ushort4*)&Yh[base + 4] = h4b;
    *(ushort4*)&Yl[base]     = l4a;
    *(ushort4*)&Yl[base + 4] = l4b;
  }
}

// ---------------------------------------------------------------------------
extern "C" void kernel_launch(void* const* d_in, const int* in_sizes, int n_in,
                              void* d_out, int out_size, void* d_ws, size_t ws_size,
                              hipStream_t stream) {
  const float* hs = (const float*)d_in[0];
  const float* Wq = (const float*)d_in[1];
  const float* Wk = (const float*)d_in[2];
  const float* Wv = (const float*)d_in[3];
  const float* Wo = (const float*)d_in[4];
  float* out = (float*)d_out;

  char* ws = (char*)d_ws;
  const size_t MB = 1 << 20;
  ushort* Ah   = (ushort*)(ws + 0 * MB);        // 4 MB hs_hi -> later Ys_hi
  ushort* Al   = (ushort*)(ws + 4 * MB);        // 4 MB hs_lo -> later Ys_lo
  ushort* Bh   = (ushort*)(ws + 8 * MB);        // 2 MB WvT_hi
  ushort* Bl   = (ushort*)(ws + 10 * MB);       // 2 MB WvT_lo
  signed char* A8 = (signed char*)(ws + 0 * MB);   // 10 MB (overlays Ah/Al/Bh after V-GEMM)
  signed char* W8 = (signed char*)(ws + 10 * MB);  // 2.5 MB (overlays Bl)
  float*  Vb   = (float*)(ws + 13 * MB);        // 8 MB
  float*  Qb   = (float*)(ws + 21 * MB);        // 2 MB
  float*  Kb   = (float*)(ws + 23 * MB);        // 2 MB
  float*  S    = (float*)(ws + 25 * MB);        // 1 MB
  ushort* WoTh = (ushort*)(ws + 26 * MB);       // 2 MB
  ushort* WoTl = (ushort*)(ws + 28 * MB);       // 2 MB  (peak 30 MB)
  double* KS   = (double*)d_out;                // 32 KB scratch, retired by step 9

  // 1) hs -> bf16 hi/lo
  split_hs<<<dim3(L * D / 4 / 256), 256, 0, stream>>>(hs, Ah, Al);
  // 2) Wv + Wo -> transposed bf16 hi/lo (fused, z=2)
  wsplit_t2<<<dim3(32, 32, 2), 256, 0, stream>>>(Wv, Wo, Bh, Bl, WoTh, WoTl);
  // 3) V projection (double-buffered split GEMM, XCD-swizzled)
  gemm_split_bf16_db<<<dim3(16, 32), 256, 0, stream>>>(Ah, Al, Bh, Bl, Vb, L, 1024, D);
  // 4) int8 5-slice splits (overwrite hs/Wv split buffers, now dead)
  split_i8_hs<<<dim3(L * D / 4 / 256), 256, 0, stream>>>(hs, A8);
  wsplit_i8<<<dim3(16, 32), 256, 0, stream>>>(Wq, Wk, W8);
  // 5) exact QK projection via i8 MFMA (XCD-swizzled)
  gemm_qk_i8<<<dim3(8, 32), 512, 0, stream>>>(A8, W8, Qb, Kb);
  // 6) per-chunk k^T v states + fp64 k sums
  chunk_state<<<dim3(NC, H), 256, 0, stream>>>(Kb, Vb, S, KS);
  // 7) in-place exclusive prefix over chunks
  prefix_state<<<H, 1024, 0, stream>>>(S, KS);
  // 8) fused chunk attention v3 (balanced) -> Ys hi/lo
  attn_chunk_v3<<<dim3(NC, H), 512, 0, stream>>>(Qb, Kb, Vb, S, KS, Ah, Al);
  // 9) output projection (fully overwrites d_out, retiring KS scratch)
  gemm_split_bf16_db<<<dim3(16, 32), 256, 0, stream>>>(Ah, Al, WoTh, WoTl, out, L, D, H * HD);
}

// Round 10
// 103.879 us; speedup vs baseline: 3.1185x; 1.1892x over previous
//
#include <hip/hip_runtime.h>

// Problem constants (B=1)
constexpr int L  = 2048;
constexpr int D  = 1024;
constexpr int H  = 16;
constexpr int F  = 16;   // qk feature dim per head
constexpr int HD = 64;   // v head dim
constexpr int CHUNK = 128;
constexpr int NC = L / CHUNK;  // 16

typedef __bf16 bf16x8 __attribute__((ext_vector_type(8)));
typedef float  f32x16 __attribute__((ext_vector_type(16)));
typedef int    i32x4  __attribute__((ext_vector_type(4)));

__device__ __forceinline__ ushort f2bf(float f) {
  uint u = __builtin_bit_cast(uint, f);
  uint r = (u + 0x7FFFu + ((u >> 16) & 1u)) >> 16;
  return (ushort)r;
}

// 5-slice signed-7-bit split of fp32 (scales 2^-4,2^-11,2^-18,2^-25,2^-32).
__device__ __forceinline__ void split5(float x, signed char s[5]) {
  float t = rintf(x * 16.f);              s[0] = (signed char)t;
  float r = fmaf(t, -6.25e-2f, x);
  t = rintf(r * 2048.f);                  s[1] = (signed char)t;
  r = fmaf(t, -4.8828125e-4f, r);
  t = rintf(r * 262144.f);                s[2] = (signed char)t;
  r = fmaf(t, -3.814697265625e-6f, r);
  t = rintf(r * 33554432.f);              s[3] = (signed char)t;
  r = fmaf(t, -2.9802322387695312e-8f, r);
  t = rintf(r * 4294967296.f);            s[4] = (signed char)t;
}

// ---------------------------------------------------------------------------
// Fused: hs fp32 -> Ah bf16 (V-GEMM A side) + A8 5-plane int8 (QK A side).
// One pass over hs. Grid 2048 x 256.
// ---------------------------------------------------------------------------
__global__ __launch_bounds__(256) void split_hs_i8(
    const float* __restrict__ X, ushort* __restrict__ Ah, signed char* __restrict__ A8) {
  const int plane = L * D;
  int idx = blockIdx.x * 256 + threadIdx.x;
  if (idx >= plane / 4) return;
  float4 v = ((const float4*)X)[idx];
  ushort4 hh;
  hh.x = f2bf(v.x); hh.y = f2bf(v.y); hh.z = f2bf(v.z); hh.w = f2bf(v.w);
  ((ushort4*)Ah)[idx] = hh;
  signed char sx[5], sy[5], sz[5], sw[5];
  split5(v.x, sx); split5(v.y, sy); split5(v.z, sz); split5(v.w, sw);
  #pragma unroll
  for (int s = 0; s < 5; ++s) {
    char4 c; c.x = sx[s]; c.y = sy[s]; c.z = sz[s]; c.w = sw[s];
    ((char4*)(A8 + (size_t)s * plane))[idx] = c;
  }
}

// ---------------------------------------------------------------------------
// Fused weight prep: z=0: Wv -> BvT bf16 [n][k]; z=1: Wo -> BoT; z=2 (x<16):
// [Wq|Wk] -> 5-slice int8 W8[s][512][1024] transposed. Grid (32,32,3).
// ---------------------------------------------------------------------------
__global__ __launch_bounds__(256) void wsplit_all(
    const float* __restrict__ Wv, const float* __restrict__ Wo,
    const float* __restrict__ Wq, const float* __restrict__ Wk,
    ushort* __restrict__ BvT, ushort* __restrict__ BoT, signed char* __restrict__ W8) {
  __shared__ float t[32][33];
  const int tid = threadIdx.x;
  const int lx = tid & 31, ly = tid >> 5;
  if (blockIdx.z == 2) {
    if (blockIdx.x >= 16) return;
    const int plane = 512 * 1024;
    const int bn = blockIdx.x * 32, bk = blockIdx.y * 32;
    const float* W = (bn < 256) ? Wq : Wk;
    const int wn = bn & 255;
    #pragma unroll
    for (int i = 0; i < 32; i += 8)
      t[ly + i][lx] = W[(size_t)(bk + ly + i) * 256 + wn + lx];
    __syncthreads();
    #pragma unroll
    for (int i = 0; i < 32; i += 8) {
      float v = t[lx][ly + i];
      signed char s[5];
      split5(v, s);
      size_t base = (size_t)(bn + ly + i) * 1024 + bk + lx;
      #pragma unroll
      for (int si = 0; si < 5; ++si) W8[(size_t)si * plane + base] = s[si];
    }
    return;
  }
  const float* W = blockIdx.z ? Wo : Wv;
  ushort* BT = blockIdx.z ? BoT : BvT;
  const int bn = blockIdx.x * 32, bk = blockIdx.y * 32;
  #pragma unroll
  for (int i = 0; i < 32; i += 8)
    t[ly + i][lx] = W[(size_t)(bk + ly + i) * 1024 + bn + lx];
  __syncthreads();
  #pragma unroll
  for (int i = 0; i < 32; i += 8) {
    float v = t[lx][ly + i];
    BT[(size_t)(bn + ly + i) * 1024 + bk + lx] = f2bf(v);
  }
}

// ---------------------------------------------------------------------------
// Plain bf16 single-product GEMM (numerator path: ~0.4% rel error, inside
// budget). Structure = proven gemm_split_bf16_db minus the lo streams.
// Tile 64x64, BK=32, 4 waves (wave 32x32, mfma_f32_32x32x16_bf16), dbuf,
// XCD swizzle (grid 512 %8==0).
// ---------------------------------------------------------------------------
__global__ __launch_bounds__(256) void gemm_bf16_db(
    const ushort* __restrict__ A, const ushort* __restrict__ BT,
    float* __restrict__ C, int M, int N, int K) {
  constexpr int LDT = 40;
  __shared__ __bf16 As[2][64][LDT];
  __shared__ __bf16 Bs[2][64][LDT];
  const int tid  = threadIdx.x;
  const int wave = tid >> 6, lane = tid & 63;
  const int wr = (wave >> 1) * 32, wc = (wave & 1) * 32;
  const int nbx = gridDim.x, nwg = gridDim.x * gridDim.y;
  int bid = blockIdx.y * nbx + blockIdx.x;
  bid = (bid & 7) * (nwg >> 3) + (bid >> 3);
  const int brow = (bid / nbx) * 64, bcol = (bid % nbx) * 64;
  const int srow = tid >> 2, skg = (tid & 3) * 8;
  const size_t a_off = (size_t)(brow + srow) * K + skg;
  const size_t b_off = (size_t)(bcol + srow) * K + skg;

  f32x16 acc;
  #pragma unroll
  for (int i = 0; i < 16; ++i) acc[i] = 0.f;

  bf16x8 ra, rb;
  auto LOADT = [&](int k0) {
    ra = *(const bf16x8*)&A[a_off + k0];
    rb = *(const bf16x8*)&BT[b_off + k0];
  };
  auto WRITET = [&](int buf) {
    *(bf16x8*)&As[buf][srow][skg] = ra;
    *(bf16x8*)&Bs[buf][srow][skg] = rb;
  };

  const int NS = K / 32;
  LOADT(0); WRITET(0);
  __syncthreads();
  int cur = 0;
  for (int t = 0; t < NS; ++t) {
    if (t + 1 < NS) LOADT((t + 1) * 32);
    const int fr = lane & 31;
    const int kh = (lane >> 5) * 8;
    bf16x8 a0 = *(const bf16x8*)&As[cur][wr + fr][kh];
    bf16x8 a1 = *(const bf16x8*)&As[cur][wr + fr][16 + kh];
    bf16x8 b0 = *(const bf16x8*)&Bs[cur][wc + fr][kh];
    bf16x8 b1 = *(const bf16x8*)&Bs[cur][wc + fr][16 + kh];
    acc = __builtin_amdgcn_mfma_f32_32x32x16_bf16(a0, b0, acc, 0, 0, 0);
    acc = __builtin_amdgcn_mfma_f32_32x32x16_bf16(a1, b1, acc, 0, 0, 0);
    if (t + 1 < NS) WRITET(cur ^ 1);
    __syncthreads();
    cur ^= 1;
  }
  const int fr = lane & 31, fq = lane >> 5;
  #pragma unroll
  for (int r = 0; r < 16; ++r) {
    int row = brow + wr + (r & 3) + 8 * (r >> 2) + 4 * fq;
    C[(size_t)row * N + bcol + wc + fr] = acc[r];
  }
}

// ---------------------------------------------------------------------------
// Exact QK projection via int8 MFMA (Ozaki 5-slice).  [proven rounds 7-9]
// ---------------------------------------------------------------------------
__global__ __launch_bounds__(512) void gemm_qk_i8(
    const signed char* __restrict__ A8, const signed char* __restrict__ W8,
    float* __restrict__ Qo, float* __restrict__ Ko) {
  constexpr int LDT = 80;
  __shared__ signed char As[5][64][LDT];
  __shared__ signed char Bs[5][64][LDT];
  const int aplane = L * D;
  const int bplane = 512 * 1024;
  const int tid  = threadIdx.x;
  const int wave = tid >> 6, lane = tid & 63;
  const int wm = (wave >> 2) * 32;
  const int wn = (wave & 3) * 16;
  const int nbx = gridDim.x, nwg = gridDim.x * gridDim.y;
  int bid = blockIdx.y * nbx + blockIdx.x;
  bid = (bid & 7) * (nwg >> 3) + (bid >> 3);
  const int brow = (bid / nbx) * 64, bcol = (bid % nbx) * 64;
  const int fr = lane & 15, kq = (lane >> 4) * 16;

  i32x4 acc[2][5];
  #pragma unroll
  for (int fm = 0; fm < 2; ++fm)
    #pragma unroll
    for (int g = 0; g < 5; ++g)
      #pragma unroll
      for (int r = 0; r < 4; ++r) acc[fm][g][r] = 0;

  for (int k0 = 0; k0 < D; k0 += 64) {
    #pragma unroll
    for (int i = 0; i < 5; ++i) {
      int c = i * 512 + tid;
      int side = (c >= 1280);
      int cc = side ? c - 1280 : c;
      int slice = cc >> 8, row = (cc & 255) >> 2, c16 = (cc & 3) * 16;
      const signed char* src = side
          ? &W8[(size_t)slice * bplane + (size_t)(bcol + row) * 1024 + k0 + c16]
          : &A8[(size_t)slice * aplane + (size_t)(brow + row) * 1024 + k0 + c16];
      int4 val = *(const int4*)src;
      signed char* dst = side ? &Bs[slice][row][c16] : &As[slice][row][c16];
      *(int4*)dst = val;
    }
    __syncthreads();
    i32x4 bfr[5], afr[2][5];
    #pragma unroll
    for (int s = 0; s < 5; ++s) bfr[s] = *(const i32x4*)&Bs[s][wn + fr][kq];
    #pragma unroll
    for (int fm = 0; fm < 2; ++fm)
      #pragma unroll
      for (int s = 0; s < 5; ++s)
        afr[fm][s] = *(const i32x4*)&As[s][wm + fm * 16 + fr][kq];
    #pragma unroll
    for (int fm = 0; fm < 2; ++fm) {
      acc[fm][0] = __builtin_amdgcn_mfma_i32_16x16x64_i8(afr[fm][0], bfr[0], acc[fm][0], 0, 0, 0);
      #pragma unroll
      for (int g = 1; g < 5; ++g)
        #pragma unroll
        for (int i = 0; i <= g; ++i)
          acc[fm][g] = __builtin_amdgcn_mfma_i32_16x16x64_i8(afr[fm][i], bfr[g - i], acc[fm][g], 0, 0, 0);
    }
    __syncthreads();
  }
  const double sc0 = 3.90625e-3, sc1 = 3.0517578125e-5, sc2 = 2.384185791015625e-7,
               sc3 = 1.862645149230957e-9, sc4 = 1.4551915228366852e-11;
  float* Out = (bcol < 256) ? Qo : Ko;
  const int ocol = (bcol & 255) + wn + fr;
  #pragma unroll
  for (int fm = 0; fm < 2; ++fm)
    #pragma unroll
    for (int r = 0; r < 4; ++r) {
      double v = (double)acc[fm][0][r] * sc0 + (double)acc[fm][1][r] * sc1 +
                 (double)acc[fm][2][r] * sc2 + (double)acc[fm][3][r] * sc3 +
                 (double)acc[fm][4][r] * sc4;
      int row = brow + wm + fm * 16 + (lane >> 4) * 4 + r;
      Out[(size_t)row * 256 + ocol] = (float)v;
    }
}

// ---------------------------------------------------------------------------
// Per-chunk state sums  [proven]. Grid (NC, H), 256 threads.
// ---------------------------------------------------------------------------
__global__ __launch_bounds__(256) void chunk_state(
    const float* __restrict__ Kq, const float* __restrict__ V,
    float* __restrict__ S, double* __restrict__ KS) {
  const int c = blockIdx.x, h = blockIdx.y;
  __shared__ float Ks[CHUNK][F];
  __shared__ float Vs[CHUNK][HD];
  const int tid = threadIdx.x;
  #pragma unroll
  for (int i = 0; i < 2; ++i) {
    int g = i * 256 + tid;
    int m = g >> 2, f0 = (g & 3) * 4;
    *(float4*)&Ks[m][f0] = *(const float4*)&Kq[(size_t)(c * CHUNK + m) * (H * F) + h * F + f0];
  }
  #pragma unroll
  for (int i = 0; i < 8; ++i) {
    int g = i * 256 + tid;
    int m = g >> 4, e0 = (g & 15) * 4;
    *(float4*)&Vs[m][e0] = *(const float4*)&V[(size_t)(c * CHUNK + m) * (H * HD) + h * HD + e0];
  }
  __syncthreads();
  const int f = tid >> 4, e0 = (tid & 15) * 4;
  float4 acc = make_float4(0.f, 0.f, 0.f, 0.f);
  for (int m = 0; m < CHUNK; ++m) {
    float kv = Ks[m][f];
    float4 v4 = *(const float4*)&Vs[m][e0];
    acc.x = fmaf(kv, v4.x, acc.x);
    acc.y = fmaf(kv, v4.y, acc.y);
    acc.z = fmaf(kv, v4.z, acc.z);
    acc.w = fmaf(kv, v4.w, acc.w);
  }
  *(float4*)&S[((((size_t)h * NC) + c) * F + f) * HD + e0] = acc;
  if (tid < F) {
    double s = 0.0;
    for (int m = 0; m < CHUNK; ++m) s += (double)Ks[m][tid];
    KS[(((size_t)h * NC) + c) * F + tid] = s;
  }
}

// ---------------------------------------------------------------------------
// Fused chunk attention v4: v3's proven balanced-pair body + on-the-fly
// exclusive prefix over chunk sums (replaces prefix_state) + single-bf16 Ys.
// Grid (NC, H), 512 threads.
// ---------------------------------------------------------------------------
__global__ __launch_bounds__(512) void attn_chunk_v4(
    const float* __restrict__ Q, const float* __restrict__ Kq, const float* __restrict__ V,
    const float* __restrict__ S, const double* __restrict__ KS,
    ushort* __restrict__ Yh) {
  const int c = blockIdx.x, h = blockIdx.y;
  __shared__ float Ks[CHUNK][F];
  __shared__ float Vs[CHUNK][HD];
  __shared__ float Ss[F][HD];     // exclusive prefix of S over chunks < c
  __shared__ double kcs[F];       // exclusive prefix of KS
  __shared__ float zs[CHUNK];
  const int tid = threadIdx.x;

  {  // Ks: 512 float4, 1/thread
    int m = tid >> 2, f0 = (tid & 3) * 4;
    *(float4*)&Ks[m][f0] = *(const float4*)&Kq[(size_t)(c * CHUNK + m) * (H * F) + h * F + f0];
  }
  #pragma unroll
  for (int i = 0; i < 4; ++i) {  // Vs: 2048 float4, 4/thread
    int g = i * 512 + tid;
    int m = g >> 4, e0 = (g & 15) * 4;
    *(float4*)&Vs[m][e0] = *(const float4*)&V[(size_t)(c * CHUNK + m) * (H * HD) + h * HD + e0];
  }
  {  // on-the-fly exclusive prefix: Ss = sum_{c'<c} S[h][c'] (2 elems/thread)
    float s0 = 0.f, s1 = 0.f;
    for (int cc = 0; cc < c; ++cc) {
      size_t base = (((size_t)h * NC) + cc) * (F * HD);
      s0 += S[base + tid];
      s1 += S[base + tid + 512];
    }
    ((float*)Ss)[tid] = s0;
    ((float*)Ss)[tid + 512] = s1;
  }
  if (tid < F) {
    double rk = 0.0;
    for (int cc = 0; cc < c; ++cc) rk += KS[(((size_t)h * NC) + cc) * F + tid];
    kcs[tid] = rk;
  }
  __syncthreads();

  const int w = tid >> 6;
  const int lane = tid & 63;
  const int rsub = lane >> 3;
  const int cg = lane & 7;
  const int e0 = cg * 8;
  const int lr = 8 * w + rsub;
  const int hr = 120 - 8 * w + rsub;

  float ql[F], qh[F];
  #pragma unroll
  for (int f0 = 0; f0 < F; f0 += 4) {
    *(float4*)&ql[f0] = *(const float4*)&Q[(size_t)(c * CHUNK + lr) * (H * F) + h * F + f0];
    *(float4*)&qh[f0] = *(const float4*)&Q[(size_t)(c * CHUNK + hr) * (H * F) + h * F + f0];
  }

  float accl[8], acch[8];
  #pragma unroll
  for (int j = 0; j < 8; ++j) { accl[j] = 0.f; acch[j] = 0.f; }
  float denl = 0.f, denh = 0.f;

  const int m1 = 8 * w + 8;
  const int m2 = 128 - 8 * w;
  for (int m = 0; m < m2; ++m) {
    float kr[F];
    #pragma unroll
    for (int f0 = 0; f0 < F; f0 += 4)
      *(float4*)&kr[f0] = *(const float4*)&Ks[m][f0];
    float v8[8];
    *(float4*)&v8[0] = *(const float4*)&Vs[m][e0];
    *(float4*)&v8[4] = *(const float4*)&Vs[m][e0 + 4];
    {
      float s = 0.f;
      #pragma unroll
      for (int f = 0; f < F; ++f) s = fmaf(qh[f], kr[f], s);
      float a = (m <= hr) ? s : 0.f;
      denh += a;
      #pragma unroll
      for (int j = 0; j < 8; ++j) acch[j] = fmaf(a, v8[j], acch[j]);
    }
    if (m < m1) {
      float s = 0.f;
      #pragma unroll
      for (int f = 0; f < F; ++f) s = fmaf(ql[f], kr[f], s);
      float a = (m <= lr) ? s : 0.f;
      denl += a;
      #pragma unroll
      for (int j = 0; j < 8; ++j) accl[j] = fmaf(a, v8[j], accl[j]);
    }
  }

  #pragma unroll
  for (int f = 0; f < F; ++f) {
    float s8[8];
    *(float4*)&s8[0] = *(const float4*)&Ss[f][e0];
    *(float4*)&s8[4] = *(const float4*)&Ss[f][e0 + 4];
    #pragma unroll
    for (int j = 0; j < 8; ++j) {
      accl[j] = fmaf(ql[f], s8[j], accl[j]);
      acch[j] = fmaf(qh[f], s8[j], acch[j]);
    }
  }

  if (cg == 0) {
    double dl = (double)denl, dh = (double)denh;
    #pragma unroll
    for (int f = 0; f < F; ++f) {
      dl += (double)ql[f] * kcs[f];
      dh += (double)qh[f] * kcs[f];
    }
    zs[lr] = (float)(1.0 / (dl + 1e-12));
    zs[hr] = (float)(1.0 / (dh + 1e-12));
  }
  __syncthreads();

  #pragma unroll
  for (int rr = 0; rr < 2; ++rr) {
    const int row = rr ? hr : lr;
    const float* ac = rr ? acch : accl;
    float zz = zs[row];
    ushort4 h4a, h4b;
    h4a.x = f2bf(ac[0] * zz); h4a.y = f2bf(ac[1] * zz);
    h4a.z = f2bf(ac[2] * zz); h4a.w = f2bf(ac[3] * zz);
    h4b.x = f2bf(ac[4] * zz); h4b.y = f2bf(ac[5] * zz);
    h4b.z = f2bf(ac[6] * zz); h4b.w = f2bf(ac[7] * zz);
    size_t base = (size_t)(c * CHUNK + row) * 1024 + h * HD + e0;
    *(ushort4*)&Yh[base]     = h4a;
    *(ushort4*)&Yh[base + 4] = h4b;
  }
}

// ---------------------------------------------------------------------------
extern "C" void kernel_launch(void* const* d_in, const int* in_sizes, int n_in,
                              void* d_out, int out_size, void* d_ws, size_t ws_size,
                              hipStream_t stream) {
  const float* hs = (const float*)d_in[0];
  const float* Wq = (const float*)d_in[1];
  const float* Wk = (const float*)d_in[2];
  const float* Wv = (const float*)d_in[3];
  const float* Wo = (const float*)d_in[4];
  float* out = (float*)d_out;

  char* ws = (char*)d_ws;
  const size_t MB = 1 << 20;
  signed char* A8 = (signed char*)(ws + 0 * MB);   // 10 MB, dead after qk (step 4)
  signed char* W8 = (signed char*)(ws + 10 * MB);  // 2.5 MB, dead after step 4
  ushort* Ah  = (ushort*)(ws + 13 * MB);           // 4 MB hs_hi, dead after step 3
  ushort* BvT = (ushort*)(ws + 17 * MB);           // 2 MB
  ushort* BoT = (ushort*)(ws + 19 * MB);           // 2 MB
  float*  Vb  = (float*)(ws + 21 * MB);            // 8 MB
  float*  Qb  = (float*)(ws + 29 * MB);            // 2 MB  (peak 31 MB)
  float*  S   = (float*)(ws + 13 * MB);            // 1 MB, overlays dead Ah (step 5+)
  ushort* Ys  = (ushort*)(ws + 0 * MB);            // 4 MB bf16, overlays dead A8 (step 6+)
  // d_out as scratch (proven pattern): fully overwritten by step 7.
  double* KS  = (double*)d_out;                    // 32 KB
  float*  Kb  = (float*)((char*)d_out + 1 * MB);   // 2 MB

  // 1) hs -> Ah bf16 + A8 int8x5 (single pass)
  split_hs_i8<<<dim3(L * D / 4 / 256), 256, 0, stream>>>(hs, Ah, A8);
  // 2) all weight prep: BvT, BoT bf16; W8 int8x5
  wsplit_all<<<dim3(32, 32, 3), 256, 0, stream>>>(Wv, Wo, Wq, Wk, BvT, BoT, W8);
  // 3) V projection (single-product bf16 GEMM)
  gemm_bf16_db<<<dim3(16, 32), 256, 0, stream>>>(Ah, BvT, Vb, L, 1024, D);
  // 4) exact QK projection via i8 MFMA
  gemm_qk_i8<<<dim3(8, 32), 512, 0, stream>>>(A8, W8, Qb, Kb);
  // 5) per-chunk k^T v states + fp64 k sums (raw, no prefix)
  chunk_state<<<dim3(NC, H), 256, 0, stream>>>(Kb, Vb, S, KS);
  // 6) fused chunk attention v4 (on-the-fly prefix) -> Ys bf16
  attn_chunk_v4<<<dim3(NC, H), 512, 0, stream>>>(Qb, Kb, Vb, S, KS, Ys);
  // 7) output projection (overwrites d_out, retiring KS/Kb scratch)
  gemm_bf16_db<<<dim3(16, 32), 256, 0, stream>>>(Ys, BoT, out, L, D, H * HD);
}

// Round 11
// 91.272 us; speedup vs baseline: 3.5493x; 1.1381x over previous
//
#include <hip/hip_runtime.h>

// Problem constants (B=1)
constexpr int L  = 2048;
constexpr int D  = 1024;
constexpr int H  = 16;
constexpr int F  = 16;   // qk feature dim per head
constexpr int HD = 64;   // v head dim
constexpr int CHUNK = 128;
constexpr int NC = L / CHUNK;  // 16

typedef __bf16 bf16x8 __attribute__((ext_vector_type(8)));
typedef float  f32x16 __attribute__((ext_vector_type(16)));
typedef int    i32x4  __attribute__((ext_vector_type(4)));

__device__ __forceinline__ ushort f2bf(float f) {
  uint u = __builtin_bit_cast(uint, f);
  uint r = (u + 0x7FFFu + ((u >> 16) & 1u)) >> 16;
  return (ushort)r;
}

// 5-slice signed-7-bit split of fp32 (scales 2^-4,2^-11,2^-18,2^-25,2^-32).
__device__ __forceinline__ void split5(float x, signed char s[5]) {
  float t = rintf(x * 16.f);              s[0] = (signed char)t;
  float r = fmaf(t, -6.25e-2f, x);
  t = rintf(r * 2048.f);                  s[1] = (signed char)t;
  r = fmaf(t, -4.8828125e-4f, r);
  t = rintf(r * 262144.f);                s[2] = (signed char)t;
  r = fmaf(t, -3.814697265625e-6f, r);
  t = rintf(r * 33554432.f);              s[3] = (signed char)t;
  r = fmaf(t, -2.9802322387695312e-8f, r);
  t = rintf(r * 4294967296.f);            s[4] = (signed char)t;
}

// ---------------------------------------------------------------------------
// Fused prep (steps 1+2 of round 10, bodies verbatim, blockIdx remapped):
// blocks [0,2048): hs -> Ah bf16 + A8 int8x5.
// blocks [2048,5120): z=(b-2048)>>10: z=0 Wv->BvT, z=1 Wo->BoT, z=2 Wq|Wk->W8.
// ---------------------------------------------------------------------------
__global__ __launch_bounds__(256) void prep_all(
    const float* __restrict__ X,
    const float* __restrict__ Wv, const float* __restrict__ Wo,
    const float* __restrict__ Wq, const float* __restrict__ Wk,
    ushort* __restrict__ Ah, signed char* __restrict__ A8,
    ushort* __restrict__ BvT, ushort* __restrict__ BoT, signed char* __restrict__ W8) {
  __shared__ float t[32][33];
  const int tid = threadIdx.x;
  const int b = blockIdx.x;
  if (b < 2048) {
    const int plane = L * D;
    int idx = b * 256 + tid;
    float4 v = ((const float4*)X)[idx];
    ushort4 hh;
    hh.x = f2bf(v.x); hh.y = f2bf(v.y); hh.z = f2bf(v.z); hh.w = f2bf(v.w);
    ((ushort4*)Ah)[idx] = hh;
    signed char sx[5], sy[5], sz[5], sw[5];
    split5(v.x, sx); split5(v.y, sy); split5(v.z, sz); split5(v.w, sw);
    #pragma unroll
    for (int s = 0; s < 5; ++s) {
      char4 c; c.x = sx[s]; c.y = sy[s]; c.z = sz[s]; c.w = sw[s];
      ((char4*)(A8 + (size_t)s * plane))[idx] = c;
    }
    return;
  }
  const int bb = b - 2048;
  const int z = bb >> 10;
  const int bx = (bb & 1023) & 31, by = (bb & 1023) >> 5;
  const int lx = tid & 31, ly = tid >> 5;
  if (z == 2) {
    if (bx >= 16) return;
    const int plane = 512 * 1024;
    const int bn = bx * 32, bk = by * 32;
    const float* W = (bn < 256) ? Wq : Wk;
    const int wn = bn & 255;
    #pragma unroll
    for (int i = 0; i < 32; i += 8)
      t[ly + i][lx] = W[(size_t)(bk + ly + i) * 256 + wn + lx];
    __syncthreads();
    #pragma unroll
    for (int i = 0; i < 32; i += 8) {
      float v = t[lx][ly + i];
      signed char s[5];
      split5(v, s);
      size_t base = (size_t)(bn + ly + i) * 1024 + bk + lx;
      #pragma unroll
      for (int si = 0; si < 5; ++si) W8[(size_t)si * plane + base] = s[si];
    }
    return;
  }
  const float* W = z ? Wo : Wv;
  ushort* BT = z ? BoT : BvT;
  const int bn = bx * 32, bk = by * 32;
  #pragma unroll
  for (int i = 0; i < 32; i += 8)
    t[ly + i][lx] = W[(size_t)(bk + ly + i) * 1024 + bn + lx];
  __syncthreads();
  #pragma unroll
  for (int i = 0; i < 32; i += 8) {
    float v = t[lx][ly + i];
    BT[(size_t)(bn + ly + i) * 1024 + bk + lx] = f2bf(v);
  }
}

// ---------------------------------------------------------------------------
// Fused independent GEMMs (steps 3+4): blocks [0,256) = exact QK via i8 MFMA
// (round-7-9 proven body verbatim, LDS via union); blocks [256,512) =
// V projection bf16 (proven fragment pattern, 128x64 tile, 8 waves, dbuf).
// 512 threads; LDS union 51.2 KB -> 3 blocks/CU.
// ---------------------------------------------------------------------------
__global__ __launch_bounds__(512) void gemm_v_qk(
    const signed char* __restrict__ A8, const signed char* __restrict__ W8,
    float* __restrict__ Qo, float* __restrict__ Ko,
    const ushort* __restrict__ Av, const ushort* __restrict__ BvT,
    float* __restrict__ Vb) {
  __shared__ __align__(16) char lds_raw[51200];
  const int tid = threadIdx.x;
  const int bid = blockIdx.x;
  const int wave = tid >> 6, lane = tid & 63;

  if (bid < 256) {
    // ---------------- exact QK (Ozaki 5-slice i8) -- proven body ----------
    auto As = (signed char (*)[64][80])(lds_raw);           // [5][64][80]
    auto Bs = (signed char (*)[64][80])(lds_raw + 25600);
    const int aplane = L * D;
    const int bplane = 512 * 1024;
    const int wm = (wave >> 2) * 32;
    const int wn = (wave & 3) * 16;
    int b2 = (bid & 7) * 32 + (bid >> 3);                   // XCD swizzle
    const int brow = (b2 >> 3) * 64, bcol = (b2 & 7) * 64;
    const int fr = lane & 15, kq = (lane >> 4) * 16;

    i32x4 acc[2][5];
    #pragma unroll
    for (int fm = 0; fm < 2; ++fm)
      #pragma unroll
      for (int g = 0; g < 5; ++g)
        #pragma unroll
        for (int r = 0; r < 4; ++r) acc[fm][g][r] = 0;

    for (int k0 = 0; k0 < D; k0 += 64) {
      #pragma unroll
      for (int i = 0; i < 5; ++i) {
        int c = i * 512 + tid;
        int side = (c >= 1280);
        int cc = side ? c - 1280 : c;
        int slice = cc >> 8, row = (cc & 255) >> 2, c16 = (cc & 3) * 16;
        const signed char* src = side
            ? &W8[(size_t)slice * bplane + (size_t)(bcol + row) * 1024 + k0 + c16]
            : &A8[(size_t)slice * aplane + (size_t)(brow + row) * 1024 + k0 + c16];
        int4 val = *(const int4*)src;
        signed char* dst = side ? &Bs[slice][row][c16] : &As[slice][row][c16];
        *(int4*)dst = val;
      }
      __syncthreads();
      i32x4 bfr[5], afr[2][5];
      #pragma unroll
      for (int s = 0; s < 5; ++s) bfr[s] = *(const i32x4*)&Bs[s][wn + fr][kq];
      #pragma unroll
      for (int fm = 0; fm < 2; ++fm)
        #pragma unroll
        for (int s = 0; s < 5; ++s)
          afr[fm][s] = *(const i32x4*)&As[s][wm + fm * 16 + fr][kq];
      #pragma unroll
      for (int fm = 0; fm < 2; ++fm) {
        acc[fm][0] = __builtin_amdgcn_mfma_i32_16x16x64_i8(afr[fm][0], bfr[0], acc[fm][0], 0, 0, 0);
        #pragma unroll
        for (int g = 1; g < 5; ++g)
          #pragma unroll
          for (int i = 0; i <= g; ++i)
            acc[fm][g] = __builtin_amdgcn_mfma_i32_16x16x64_i8(afr[fm][i], bfr[g - i], acc[fm][g], 0, 0, 0);
      }
      __syncthreads();
    }
    const double sc0 = 3.90625e-3, sc1 = 3.0517578125e-5, sc2 = 2.384185791015625e-7,
                 sc3 = 1.862645149230957e-9, sc4 = 1.4551915228366852e-11;
    float* Out = (bcol < 256) ? Qo : Ko;
    const int ocol = (bcol & 255) + wn + fr;
    #pragma unroll
    for (int fm = 0; fm < 2; ++fm)
      #pragma unroll
      for (int r = 0; r < 4; ++r) {
        double v = (double)acc[fm][0][r] * sc0 + (double)acc[fm][1][r] * sc1 +
                   (double)acc[fm][2][r] * sc2 + (double)acc[fm][3][r] * sc3 +
                   (double)acc[fm][4][r] * sc4;
        int row = brow + wm + fm * 16 + (lane >> 4) * 4 + r;
        Out[(size_t)row * 256 + ocol] = (float)v;
      }
    return;
  }

  // ---------------- V projection bf16, 128x64 tile, 8 waves, dbuf ---------
  auto AsV = (__bf16 (*)[128][40])(lds_raw);                // [2][128][40]
  auto BsV = (__bf16 (*)[64][40])(lds_raw + 20480);         // [2][64][40]
  const int vb0 = bid - 256;
  const int v2 = (vb0 & 7) * 32 + (vb0 >> 3);               // XCD swizzle
  const int brow = (v2 >> 4) * 128, bcol = (v2 & 15) * 64;
  const int wm = (wave >> 1) * 32, wn = (wave & 1) * 32;
  const int srow = tid >> 2, skg = (tid & 3) * 8;           // A: 128 rows x 4 kchunks
  const size_t a_off = (size_t)(brow + srow) * D + skg;
  const size_t b_off = (size_t)(bcol + (tid >> 2)) * D + skg;  // tid<256: 64 rows

  f32x16 acc;
  #pragma unroll
  for (int i = 0; i < 16; ++i) acc[i] = 0.f;

  bf16x8 ra, rb;
  auto LOADT = [&](int k0) {
    ra = *(const bf16x8*)&Av[a_off + k0];
    if (tid < 256) rb = *(const bf16x8*)&BvT[b_off + k0];
  };
  auto WRITET = [&](int buf) {
    *(bf16x8*)&AsV[buf][srow][skg] = ra;
    if (tid < 256) *(bf16x8*)&BsV[buf][tid >> 2][skg] = rb;
  };

  const int NS = D / 32;
  LOADT(0); WRITET(0);
  __syncthreads();
  int cur = 0;
  for (int t = 0; t < NS; ++t) {
    if (t + 1 < NS) LOADT((t + 1) * 32);
    const int fr = lane & 31;
    const int kh = (lane >> 5) * 8;
    bf16x8 a0 = *(const bf16x8*)&AsV[cur][wm + fr][kh];
    bf16x8 a1 = *(const bf16x8*)&AsV[cur][wm + fr][16 + kh];
    bf16x8 b0 = *(const bf16x8*)&BsV[cur][wn + fr][kh];
    bf16x8 b1 = *(const bf16x8*)&BsV[cur][wn + fr][16 + kh];
    acc = __builtin_amdgcn_mfma_f32_32x32x16_bf16(a0, b0, acc, 0, 0, 0);
    acc = __builtin_amdgcn_mfma_f32_32x32x16_bf16(a1, b1, acc, 0, 0, 0);
    if (t + 1 < NS) WRITET(cur ^ 1);
    __syncthreads();
    cur ^= 1;
  }
  const int fr = lane & 31, fq = lane >> 5;
  #pragma unroll
  for (int r = 0; r < 16; ++r) {
    int row = brow + wm + (r & 3) + 8 * (r >> 2) + 4 * fq;
    Vb[(size_t)row * 1024 + bcol + wn + fr] = acc[r];
  }
}

// ---------------------------------------------------------------------------
// Plain bf16 single-product GEMM  [proven round 10] (Wo projection).
// Tile 64x64, BK=32, 4 waves, dbuf, XCD swizzle (grid 512 %8==0).
// ---------------------------------------------------------------------------
__global__ __launch_bounds__(256) void gemm_bf16_db(
    const ushort* __restrict__ A, const ushort* __restrict__ BT,
    float* __restrict__ C, int M, int N, int K) {
  constexpr int LDT = 40;
  __shared__ __bf16 As[2][64][LDT];
  __shared__ __bf16 Bs[2][64][LDT];
  const int tid  = threadIdx.x;
  const int wave = tid >> 6, lane = tid & 63;
  const int wr = (wave >> 1) * 32, wc = (wave & 1) * 32;
  const int nbx = gridDim.x, nwg = gridDim.x * gridDim.y;
  int bid = blockIdx.y * nbx + blockIdx.x;
  bid = (bid & 7) * (nwg >> 3) + (bid >> 3);
  const int brow = (bid / nbx) * 64, bcol = (bid % nbx) * 64;
  const int srow = tid >> 2, skg = (tid & 3) * 8;
  const size_t a_off = (size_t)(brow + srow) * K + skg;
  const size_t b_off = (size_t)(bcol + srow) * K + skg;

  f32x16 acc;
  #pragma unroll
  for (int i = 0; i < 16; ++i) acc[i] = 0.f;

  bf16x8 ra, rb;
  auto LOADT = [&](int k0) {
    ra = *(const bf16x8*)&A[a_off + k0];
    rb = *(const bf16x8*)&BT[b_off + k0];
  };
  auto WRITET = [&](int buf) {
    *(bf16x8*)&As[buf][srow][skg] = ra;
    *(bf16x8*)&Bs[buf][srow][skg] = rb;
  };

  const int NS = K / 32;
  LOADT(0); WRITET(0);
  __syncthreads();
  int cur = 0;
  for (int t = 0; t < NS; ++t) {
    if (t + 1 < NS) LOADT((t + 1) * 32);
    const int fr = lane & 31;
    const int kh = (lane >> 5) * 8;
    bf16x8 a0 = *(const bf16x8*)&As[cur][wr + fr][kh];
    bf16x8 a1 = *(const bf16x8*)&As[cur][wr + fr][16 + kh];
    bf16x8 b0 = *(const bf16x8*)&Bs[cur][wc + fr][kh];
    bf16x8 b1 = *(const bf16x8*)&Bs[cur][wc + fr][16 + kh];
    acc = __builtin_amdgcn_mfma_f32_32x32x16_bf16(a0, b0, acc, 0, 0, 0);
    acc = __builtin_amdgcn_mfma_f32_32x32x16_bf16(a1, b1, acc, 0, 0, 0);
    if (t + 1 < NS) WRITET(cur ^ 1);
    __syncthreads();
    cur ^= 1;
  }
  const int fr = lane & 31, fq = lane >> 5;
  #pragma unroll
  for (int r = 0; r < 16; ++r) {
    int row = brow + wr + (r & 3) + 8 * (r >> 2) + 4 * fq;
    C[(size_t)row * N + bcol + wc + fr] = acc[r];
  }
}

// ---------------------------------------------------------------------------
// Per-chunk state sums  [proven]. Grid (NC, H), 256 threads.
// ---------------------------------------------------------------------------
__global__ __launch_bounds__(256) void chunk_state(
    const float* __restrict__ Kq, const float* __restrict__ V,
    float* __restrict__ S, double* __restrict__ KS) {
  const int c = blockIdx.x, h = blockIdx.y;
  __shared__ float Ks[CHUNK][F];
  __shared__ float Vs[CHUNK][HD];
  const int tid = threadIdx.x;
  #pragma unroll
  for (int i = 0; i < 2; ++i) {
    int g = i * 256 + tid;
    int m = g >> 2, f0 = (g & 3) * 4;
    *(float4*)&Ks[m][f0] = *(const float4*)&Kq[(size_t)(c * CHUNK + m) * (H * F) + h * F + f0];
  }
  #pragma unroll
  for (int i = 0; i < 8; ++i) {
    int g = i * 256 + tid;
    int m = g >> 4, e0 = (g & 15) * 4;
    *(float4*)&Vs[m][e0] = *(const float4*)&V[(size_t)(c * CHUNK + m) * (H * HD) + h * HD + e0];
  }
  __syncthreads();
  const int f = tid >> 4, e0 = (tid & 15) * 4;
  float4 acc = make_float4(0.f, 0.f, 0.f, 0.f);
  for (int m = 0; m < CHUNK; ++m) {
    float kv = Ks[m][f];
    float4 v4 = *(const float4*)&Vs[m][e0];
    acc.x = fmaf(kv, v4.x, acc.x);
    acc.y = fmaf(kv, v4.y, acc.y);
    acc.z = fmaf(kv, v4.z, acc.z);
    acc.w = fmaf(kv, v4.w, acc.w);
  }
  *(float4*)&S[((((size_t)h * NC) + c) * F + f) * HD + e0] = acc;
  if (tid < F) {
    double s = 0.0;
    for (int m = 0; m < CHUNK; ++m) s += (double)Ks[m][tid];
    KS[(((size_t)h * NC) + c) * F + tid] = s;
  }
}

// ---------------------------------------------------------------------------
// Fused chunk attention v4  [proven round 10]. Grid (NC, H), 512 threads.
// ---------------------------------------------------------------------------
__global__ __launch_bounds__(512) void attn_chunk_v4(
    const float* __restrict__ Q, const float* __restrict__ Kq, const float* __restrict__ V,
    const float* __restrict__ S, const double* __restrict__ KS,
    ushort* __restrict__ Yh) {
  const int c = blockIdx.x, h = blockIdx.y;
  __shared__ float Ks[CHUNK][F];
  __shared__ float Vs[CHUNK][HD];
  __shared__ float Ss[F][HD];
  __shared__ double kcs[F];
  __shared__ float zs[CHUNK];
  const int tid = threadIdx.x;

  {
    int m = tid >> 2, f0 = (tid & 3) * 4;
    *(float4*)&Ks[m][f0] = *(const float4*)&Kq[(size_t)(c * CHUNK + m) * (H * F) + h * F + f0];
  }
  #pragma unroll
  for (int i = 0; i < 4; ++i) {
    int g = i * 512 + tid;
    int m = g >> 4, e0 = (g & 15) * 4;
    *(float4*)&Vs[m][e0] = *(const float4*)&V[(size_t)(c * CHUNK + m) * (H * HD) + h * HD + e0];
  }
  {
    float s0 = 0.f, s1 = 0.f;
    for (int cc = 0; cc < c; ++cc) {
      size_t base = (((size_t)h * NC) + cc) * (F * HD);
      s0 += S[base + tid];
      s1 += S[base + tid + 512];
    }
    ((float*)Ss)[tid] = s0;
    ((float*)Ss)[tid + 512] = s1;
  }
  if (tid < F) {
    double rk = 0.0;
    for (int cc = 0; cc < c; ++cc) rk += KS[(((size_t)h * NC) + cc) * F + tid];
    kcs[tid] = rk;
  }
  __syncthreads();

  const int w = tid >> 6;
  const int lane = tid & 63;
  const int rsub = lane >> 3;
  const int cg = lane & 7;
  const int e0 = cg * 8;
  const int lr = 8 * w + rsub;
  const int hr = 120 - 8 * w + rsub;

  float ql[F], qh[F];
  #pragma unroll
  for (int f0 = 0; f0 < F; f0 += 4) {
    *(float4*)&ql[f0] = *(const float4*)&Q[(size_t)(c * CHUNK + lr) * (H * F) + h * F + f0];
    *(float4*)&qh[f0] = *(const float4*)&Q[(size_t)(c * CHUNK + hr) * (H * F) + h * F + f0];
  }

  float accl[8], acch[8];
  #pragma unroll
  for (int j = 0; j < 8; ++j) { accl[j] = 0.f; acch[j] = 0.f; }
  float denl = 0.f, denh = 0.f;

  const int m1 = 8 * w + 8;
  const int m2 = 128 - 8 * w;
  for (int m = 0; m < m2; ++m) {
    float kr[F];
    #pragma unroll
    for (int f0 = 0; f0 < F; f0 += 4)
      *(float4*)&kr[f0] = *(const float4*)&Ks[m][f0];
    float v8[8];
    *(float4*)&v8[0] = *(const float4*)&Vs[m][e0];
    *(float4*)&v8[4] = *(const float4*)&Vs[m][e0 + 4];
    {
      float s = 0.f;
      #pragma unroll
      for (int f = 0; f < F; ++f) s = fmaf(qh[f], kr[f], s);
      float a = (m <= hr) ? s : 0.f;
      denh += a;
      #pragma unroll
      for (int j = 0; j < 8; ++j) acch[j] = fmaf(a, v8[j], acch[j]);
    }
    if (m < m1) {
      float s = 0.f;
      #pragma unroll
      for (int f = 0; f < F; ++f) s = fmaf(ql[f], kr[f], s);
      float a = (m <= lr) ? s : 0.f;
      denl += a;
      #pragma unroll
      for (int j = 0; j < 8; ++j) accl[j] = fmaf(a, v8[j], accl[j]);
    }
  }

  #pragma unroll
  for (int f = 0; f < F; ++f) {
    float s8[8];
    *(float4*)&s8[0] = *(const float4*)&Ss[f][e0];
    *(float4*)&s8[4] = *(const float4*)&Ss[f][e0 + 4];
    #pragma unroll
    for (int j = 0; j < 8; ++j) {
      accl[j] = fmaf(ql[f], s8[j], accl[j]);
      acch[j] = fmaf(qh[f], s8[j], acch[j]);
    }
  }

  if (cg == 0) {
    double dl = (double)denl, dh = (double)denh;
    #pragma unroll
    for (int f = 0; f < F; ++f) {
      dl += (double)ql[f] * kcs[f];
      dh += (double)qh[f] * kcs[f];
    }
    zs[lr] = (float)(1.0 / (dl + 1e-12));
    zs[hr] = (float)(1.0 / (dh + 1e-12));
  }
  __syncthreads();

  #pragma unroll
  for (int rr = 0; rr < 2; ++rr) {
    const int row = rr ? hr : lr;
    const float* ac = rr ? acch : accl;
    float zz = zs[row];
    ushort4 h4a, h4b;
    h4a.x = f2bf(ac[0] * zz); h4a.y = f2bf(ac[1] * zz);
    h4a.z = f2bf(ac[2] * zz); h4a.w = f2bf(ac[3] * zz);
    h4b.x = f2bf(ac[4] * zz); h4b.y = f2bf(ac[5] * zz);
    h4b.z = f2bf(ac[6] * zz); h4b.w = f2bf(ac[7] * zz);
    size_t base = (size_t)(c * CHUNK + row) * 1024 + h * HD + e0;
    *(ushort4*)&Yh[base]     = h4a;
    *(ushort4*)&Yh[base + 4] = h4b;
  }
}

// ---------------------------------------------------------------------------
extern "C" void kernel_launch(void* const* d_in, const int* in_sizes, int n_in,
                              void* d_out, int out_size, void* d_ws, size_t ws_size,
                              hipStream_t stream) {
  const float* hs = (const float*)d_in[0];
  const float* Wq = (const float*)d_in[1];
  const float* Wk = (const float*)d_in[2];
  const float* Wv = (const float*)d_in[3];
  const float* Wo = (const float*)d_in[4];
  float* out = (float*)d_out;

  char* ws = (char*)d_ws;
  const size_t MB = 1 << 20;
  signed char* A8 = (signed char*)(ws + 0 * MB);   // 10 MB, dead after step 2
  signed char* W8 = (signed char*)(ws + 10 * MB);  // 2.5 MB, dead after step 2
  ushort* Ah  = (ushort*)(ws + 13 * MB);           // 4 MB, dead after step 2
  ushort* BvT = (ushort*)(ws + 17 * MB);           // 2 MB
  ushort* BoT = (ushort*)(ws + 19 * MB);           // 2 MB
  float*  Vb  = (float*)(ws + 21 * MB);            // 8 MB
  float*  Qb  = (float*)(ws + 29 * MB);            // 2 MB  (peak 31 MB)
  float*  S   = (float*)(ws + 13 * MB);            // 1 MB, overlays dead Ah (step 3+)
  ushort* Ys  = (ushort*)(ws + 0 * MB);            // 4 MB bf16, overlays dead A8 (step 4+)
  // d_out as scratch (proven): fully overwritten by step 5.
  double* KS  = (double*)d_out;                    // 32 KB
  float*  Kb  = (float*)((char*)d_out + 1 * MB);   // 2 MB

  // 1) fused prep: Ah + A8 from hs; BvT, BoT, W8 from weights
  prep_all<<<dim3(5120), 256, 0, stream>>>(hs, Wv, Wo, Wq, Wk, Ah, A8, BvT, BoT, W8);
  // 2) fused independent GEMMs: exact QK (i8) + V projection (bf16)
  gemm_v_qk<<<dim3(512), 512, 0, stream>>>(A8, W8, Qb, Kb, Ah, BvT, Vb);
  // 3) per-chunk k^T v states + fp64 k sums
  chunk_state<<<dim3(NC, H), 256, 0, stream>>>(Kb, Vb, S, KS);
  // 4) fused chunk attention v4 (on-the-fly prefix) -> Ys bf16
  attn_chunk_v4<<<dim3(NC, H), 512, 0, stream>>>(Qb, Kb, Vb, S, KS, Ys);
  // 5) output projection (overwrites d_out, retiring KS/Kb scratch)
  gemm_bf16_db<<<dim3(16, 32), 256, 0, stream>>>(Ys, BoT, out, L, D, H * HD);
}